// Round 1
// baseline (154.492 us; speedup 1.0000x reference)
//
#include <hip/hip_runtime.h>

// LinearAttentionSVAR: B=2, L=2048, D=1024, H=16, d=64.
// Pipeline:
//  1. cvt4: X,Wq,Wk,Wv -> bf16
//  2. bm:   Bm[h] = tril(Ltri[h]) @ tril(Ltri[h])^T   (fp32)
//  3. wcp:  Wc'[j][h*64+dk] = sum_e Wc[j][h*64+e]*Bm[h][e][dk] -> bf16
//  4-6. gemm_bt: Q,K,V = Xb @ W^T (bf16 out, MFMA 16x16x32)
//  7. transpose: K,V [B*L][H*64] -> KT,VT [B*H][64][2048]
//  8. chunk_state: per (b,h,chunk): stateT[e][dk] = sum_t V[t,e]K[t,dk] (fp32)
//  9. prefix_state: exclusive prefix over chunks -> bf16
// 10. chunk_attn: Y = Q@stateT^T + tril(Q@K^T)@V per chunk (bf16 out)
// 11. gemm_bt<float>: out = Y @ Wc'^T (fp32)
// Workspace use: ~78 MB.

#define DEV static __device__ __forceinline__

typedef unsigned short u16;
typedef unsigned long long u64;
typedef __attribute__((ext_vector_type(4))) float f32x4;
typedef __attribute__((ext_vector_type(8))) short bf16x8;

DEV u16 f2bf(float f){
  union { float f; unsigned u; } v; v.f = f;
  unsigned r = v.u + 0x7FFFu + ((v.u >> 16) & 1u);
  return (u16)(r >> 16);
}

DEV void store_val(float* p, float v){ *p = v; }
DEV void store_val(u16* p, float v){ *p = f2bf(v); }

// ---------------- 1. fp32 -> bf16 convert (4 regions) ----------------
__global__ __launch_bounds__(256) void cvt4_kernel(
    const float* __restrict__ s0, u16* __restrict__ d0, int n0,
    const float* __restrict__ s1, u16* __restrict__ d1, int n1,
    const float* __restrict__ s2, u16* __restrict__ d2, int n2,
    const float* __restrict__ s3, u16* __restrict__ d3, int n3)
{
  int total = (n0 + n1 + n2 + n3) >> 2;
  for(int i = blockIdx.x * blockDim.x + threadIdx.x; i < total; i += gridDim.x * blockDim.x){
    int e = i << 2;
    const float* s; u16* d;
    if(e < n0){ s = s0 + e; d = d0 + e; }
    else if(e < n0 + n1){ s = s1 + (e - n0); d = d1 + (e - n0); }
    else if(e < n0 + n1 + n2){ s = s2 + (e - n0 - n1); d = d2 + (e - n0 - n1); }
    else { s = s3 + (e - n0 - n1 - n2); d = d3 + (e - n0 - n1 - n2); }
    float4 v = *(const float4*)s;
    u64 pk = (u64)f2bf(v.x) | ((u64)f2bf(v.y) << 16) | ((u64)f2bf(v.z) << 32) | ((u64)f2bf(v.w) << 48);
    *(u64*)d = pk;
  }
}

// ---------------- 2. Bm = Lm @ Lm^T ----------------
__global__ __launch_bounds__(256) void bm_kernel(const float* __restrict__ Ltri, float* __restrict__ Bm)
{
  int h = blockIdx.x;
  __shared__ float Lm[64][65];
  const float* src = Ltri + (size_t)h * 4096;
  for(int i = threadIdx.x; i < 4096; i += 256){
    int e = i >> 6, k = i & 63;
    Lm[e][k] = (k <= e) ? src[i] : 0.f;
  }
  __syncthreads();
  float* out = Bm + (size_t)h * 4096;
  for(int i = threadIdx.x; i < 4096; i += 256){
    int e = i >> 6, dk = i & 63;
    float sum = 0.f;
    int kmax = e < dk ? e : dk;
    for(int k = 0; k <= kmax; k++) sum += Lm[e][k] * Lm[dk][k];
    out[i] = sum;
  }
}

// ---------------- 3. Wc' = fold Bm into Wc ----------------
__global__ __launch_bounds__(256) void wcp_kernel(const float* __restrict__ Wc, const float* __restrict__ Bm,
                                                  u16* __restrict__ Wcpb)
{
  int j = blockIdx.x; // 0..1023
  __shared__ float row[1024];
  for(int i = threadIdx.x; i < 1024; i += 256) row[i] = Wc[(size_t)j * 1024 + i];
  __syncthreads();
  for(int cbase = 0; cbase < 1024; cbase += 256){
    int ccol = cbase + threadIdx.x;
    int h = ccol >> 6, dk = ccol & 63;
    const float* bm = Bm + (size_t)h * 4096 + dk;
    const float* wr = &row[h * 64];
    float sum = 0.f;
#pragma unroll 8
    for(int e = 0; e < 64; e++) sum += wr[e] * bm[e * 64];
    Wcpb[(size_t)j * 1024 + ccol] = f2bf(sum);
  }
}

// ---------------- 4. GEMM C[M,N] = A[M,K] @ W[N,K]^T  (bf16 in, MFMA) ----------------
// 128x128 tile, BK=32, 4 waves (2x2), each wave 64x64 via 4x4 16x16x32 frags.
template<typename OutT>
__global__ __launch_bounds__(256) void gemm_bt(
    const u16* __restrict__ A, const u16* __restrict__ W, OutT* __restrict__ C,
    int M, int N, int K)
{
  __shared__ u16 Asm[128 * 32];
  __shared__ u16 Bsm[128 * 32];
  const int t = threadIdx.x;
  const int wid = t >> 6, lane = t & 63;
  const int wr = wid >> 1, wc = wid & 1;
  const int lr = lane & 15, lk8 = (lane >> 4) * 8, lq = lane >> 4;
  const int srow = t >> 2, scol = (t & 3) * 8;
  const u16* Ag = A + (size_t)(blockIdx.x * 128 + srow) * K + scol;
  const u16* Wg = W + (size_t)(blockIdx.y * 128 + srow) * K + scol;
  f32x4 acc[4][4] = {};
  int4 pa0 = *(const int4*)(Ag);
  int4 pa1 = *(const int4*)(Ag + (size_t)64 * K);
  int4 pb0 = *(const int4*)(Wg);
  int4 pb1 = *(const int4*)(Wg + (size_t)64 * K);
  for(int k0 = 0; k0 < K; k0 += 32){
    __syncthreads();
    *(int4*)&Asm[srow * 32 + scol] = pa0;
    *(int4*)&Asm[(srow + 64) * 32 + scol] = pa1;
    *(int4*)&Bsm[srow * 32 + scol] = pb0;
    *(int4*)&Bsm[(srow + 64) * 32 + scol] = pb1;
    __syncthreads();
    if(k0 + 32 < K){
      pa0 = *(const int4*)(Ag + k0 + 32);
      pa1 = *(const int4*)(Ag + (size_t)64 * K + k0 + 32);
      pb0 = *(const int4*)(Wg + k0 + 32);
      pb1 = *(const int4*)(Wg + (size_t)64 * K + k0 + 32);
    }
    bf16x8 af[4], bfr[4];
#pragma unroll
    for(int i = 0; i < 4; i++) af[i]  = *(const bf16x8*)&Asm[(wr * 64 + i * 16 + lr) * 32 + lk8];
#pragma unroll
    for(int j = 0; j < 4; j++) bfr[j] = *(const bf16x8*)&Bsm[(wc * 64 + j * 16 + lr) * 32 + lk8];
#pragma unroll
    for(int i = 0; i < 4; i++)
#pragma unroll
      for(int j = 0; j < 4; j++)
        acc[i][j] = __builtin_amdgcn_mfma_f32_16x16x32_bf16(af[i], bfr[j], acc[i][j], 0, 0, 0);
  }
#pragma unroll
  for(int i = 0; i < 4; i++)
#pragma unroll
    for(int j = 0; j < 4; j++)
#pragma unroll
      for(int r = 0; r < 4; r++){
        int row = blockIdx.x * 128 + wr * 64 + i * 16 + lq * 4 + r;
        int col = blockIdx.y * 128 + wc * 64 + j * 16 + lr;
        store_val(C + (size_t)row * N + col, acc[i][j][r]);
      }
}

// ---------------- 7. transpose K,V: [B*L][H*64] -> [B*H][64][2048] ----------------
__global__ __launch_bounds__(256) void transpose_dl(
    const u16* __restrict__ sK, u16* __restrict__ dK,
    const u16* __restrict__ sV, u16* __restrict__ dV)
{
  const u16* src = blockIdx.y ? sV : sK;
  u16* dst = blockIdx.y ? dV : dK;
  __shared__ u16 tile[64][72];
  int bh = blockIdx.x >> 5, lt = blockIdx.x & 31;
  int b = bh >> 4, h = bh & 15;
  int t = threadIdx.x;
  int r = t >> 3;          // 0..31
  int cc = (t & 7) * 8;    // 0..56
  const u16* s = src + (size_t)(b * 2048 + lt * 64) * 1024 + h * 64;
#pragma unroll
  for(int p = 0; p < 2; p++){
    int row = r + p * 32;
    int4 v = *(const int4*)(s + (size_t)row * 1024 + cc);
    *(int4*)&tile[row][cc] = v;
  }
  __syncthreads();
  u16* dptr = dst + (size_t)bh * 64 * 2048 + lt * 64;
#pragma unroll
  for(int p = 0; p < 2; p++){
    int drow = r + p * 32;   // d index
    u16 tmp[8] __attribute__((aligned(16)));
#pragma unroll
    for(int j = 0; j < 8; j++) tmp[j] = tile[cc + j][drow];
    *(int4*)(dptr + (size_t)drow * 2048 + cc) = *(const int4*)tmp;
  }
}

// ---------------- 8. per-chunk stateT[e][dk] = sum_{t in chunk} V[t,e]*K[t,dk] ----------------
__global__ __launch_bounds__(256) void chunk_state(
    const u16* __restrict__ KT, const u16* __restrict__ VT, float* __restrict__ Sc)
{
  int bh = blockIdx.x;   // 32
  int c  = blockIdx.y;   // 16
  int t = threadIdx.x, wid = t >> 6, lane = t & 63;
  int wr = wid >> 1, wc = wid & 1;
  int lr = lane & 15, lk8 = (lane >> 4) * 8, lq = lane >> 4;
  const u16* vt = VT + (size_t)bh * 64 * 2048 + (size_t)c * 128;
  const u16* kt = KT + (size_t)bh * 64 * 2048 + (size_t)c * 128;
  f32x4 acc[2][2] = {};
#pragma unroll
  for(int ks = 0; ks < 4; ks++){
    bf16x8 a[2], b[2];
#pragma unroll
    for(int i = 0; i < 2; i++) a[i] = *(const bf16x8*)(vt + (size_t)(wr * 32 + i * 16 + lr) * 2048 + ks * 32 + lk8);
#pragma unroll
    for(int j = 0; j < 2; j++) b[j] = *(const bf16x8*)(kt + (size_t)(wc * 32 + j * 16 + lr) * 2048 + ks * 32 + lk8);
#pragma unroll
    for(int i = 0; i < 2; i++)
#pragma unroll
      for(int j = 0; j < 2; j++)
        acc[i][j] = __builtin_amdgcn_mfma_f32_16x16x32_bf16(a[i], b[j], acc[i][j], 0, 0, 0);
  }
  float* out = Sc + ((size_t)bh * 16 + c) * 4096;
#pragma unroll
  for(int i = 0; i < 2; i++)
#pragma unroll
    for(int j = 0; j < 2; j++)
#pragma unroll
      for(int r = 0; r < 4; r++){
        int e = wr * 32 + i * 16 + lq * 4 + r, dk = wc * 32 + j * 16 + lr;
        out[e * 64 + dk] = acc[i][j][r];
      }
}

// ---------------- 9. exclusive prefix over chunks, fp32 -> bf16 ----------------
__global__ __launch_bounds__(256) void prefix_state(const float* __restrict__ Sc, u16* __restrict__ Scb)
{
  int bh = blockIdx.x >> 4, part = blockIdx.x & 15;
  int e = part * 256 + threadIdx.x; // 0..4095
  const float* s = Sc + (size_t)bh * 16 * 4096 + e;
  u16* d = Scb + (size_t)bh * 16 * 4096 + e;
  float run = 0.f;
  for(int c = 0; c < 16; c++){
    float v = s[(size_t)c * 4096];
    d[(size_t)c * 4096] = f2bf(run);
    run += v;
  }
}

// ---------------- 10. per-chunk attention: Y = Q@stateT^T + tril(Q@K^T)@V ----------------
__global__ __launch_bounds__(256) void chunk_attn(
    const u16* __restrict__ Q, const u16* __restrict__ Kmat,
    const u16* __restrict__ VT, const u16* __restrict__ Scb, u16* __restrict__ Y)
{
  int bh = blockIdx.x, c = blockIdx.y;
  int b = bh >> 4, h = bh & 15;
  int t = threadIdx.x, wid = t >> 6, lane = t & 63;
  int lr = lane & 15, lk8 = (lane >> 4) * 8, lq = lane >> 4;
  __shared__ u16 S[128 * 128];  // bf16 scores, XOR-swizzled rows
  // zero-fill (cols above the diagonal band must read as 0 in the SV phase)
#pragma unroll
  for(int i = 0; i < 16; i++) ((u64*)S)[t + i * 256] = 0ULL;
  __syncthreads();
  const u16* qg = Q    + (size_t)(b * 2048 + c * 128) * 1024 + h * 64;
  const u16* kg = Kmat + (size_t)(b * 2048 + c * 128) * 1024 + h * 64;
  // ---- phase 1: S = tril(Q @ K^T), K-dim = 64 ----
#pragma unroll
  for(int mi = 0; mi < 2; mi++){
    int mf = wid + mi * 4;        // m-frag index 0..7 (interleaved for balance)
    int Rm = mf * 16;
    bf16x8 a[2];
#pragma unroll
    for(int ks = 0; ks < 2; ks++) a[ks] = *(const bf16x8*)(qg + (size_t)(Rm + lr) * 1024 + ks * 32 + lk8);
    for(int nf = 0; nf <= mf; nf++){
      f32x4 acc = {};
#pragma unroll
      for(int ks = 0; ks < 2; ks++){
        bf16x8 bb = *(const bf16x8*)(kg + (size_t)(nf * 16 + lr) * 1024 + ks * 32 + lk8);
        acc = __builtin_amdgcn_mfma_f32_16x16x32_bf16(a[ks], bb, acc, 0, 0, 0);
      }
#pragma unroll
      for(int r = 0; r < 4; r++){
        int row = lq * 4 + r, col = lr;
        float v = acc[r];
        if(nf == mf && col > row) v = 0.f;  // causal mask on diagonal frag
        int grow = Rm + row, gcol = nf * 16 + col;
        int off = (grow * 128 + gcol) * 2;
        off ^= ((grow & 7) << 4);
        *(u16*)((char*)S + off) = f2bf(v);
      }
    }
  }
  __syncthreads();
  // ---- phase 2: Y = Q @ stateT^T  +  S @ V ----
  const u16* scb = Scb + ((size_t)bh * 16 + c) * 4096;
  const u16* vt  = VT + (size_t)bh * 64 * 2048 + (size_t)c * 128;
  u16* yg = Y + (size_t)(b * 2048 + c * 128) * 1024 + h * 64;
#pragma unroll
  for(int mi = 0; mi < 2; mi++){
    int mf = wid + mi * 4;
    int Rm = mf * 16;
    f32x4 acc[4] = {};
    // inter-chunk: Q @ stateT^T
    bf16x8 a[2];
#pragma unroll
    for(int ks = 0; ks < 2; ks++) a[ks] = *(const bf16x8*)(qg + (size_t)(Rm + lr) * 1024 + ks * 32 + lk8);
#pragma unroll
    for(int nf = 0; nf < 4; nf++){
#pragma unroll
      for(int ks = 0; ks < 2; ks++){
        bf16x8 bb = *(const bf16x8*)(scb + (nf * 16 + lr) * 64 + ks * 32 + lk8);
        acc[nf] = __builtin_amdgcn_mfma_f32_16x16x32_bf16(a[ks], bb, acc[nf], 0, 0, 0);
      }
    }
    // intra-chunk: S @ V, k-steps limited to the causal band
    int ksmax = mf >> 1;
    for(int ks = 0; ks <= ksmax; ks++){
      int row = Rm + lr;
      int off = (row * 128 + ks * 32 + lk8) * 2;
      off ^= ((row & 7) << 4);
      bf16x8 af = *(const bf16x8*)((char*)S + off);
#pragma unroll
      for(int nf = 0; nf < 4; nf++){
        bf16x8 bb = *(const bf16x8*)(vt + (size_t)(nf * 16 + lr) * 2048 + ks * 32 + lk8);
        acc[nf] = __builtin_amdgcn_mfma_f32_16x16x32_bf16(af, bb, acc[nf], 0, 0, 0);
      }
    }
#pragma unroll
    for(int nf = 0; nf < 4; nf++)
#pragma unroll
      for(int r = 0; r < 4; r++){
        int grow = Rm + lq * 4 + r, gcol = nf * 16 + lr;
        yg[(size_t)grow * 1024 + gcol] = f2bf(acc[nf][r]);
      }
  }
}

// ---------------- launch ----------------
extern "C" void kernel_launch(void* const* d_in, const int* in_sizes, int n_in,
                              void* d_out, int out_size, void* d_ws, size_t ws_size,
                              hipStream_t stream)
{
  const float* X    = (const float*)d_in[0];
  const float* Wq   = (const float*)d_in[1];
  const float* Wk   = (const float*)d_in[2];
  const float* Wv   = (const float*)d_in[3];
  const float* Wc   = (const float*)d_in[4];
  const float* Ltri = (const float*)d_in[5];
  float* out = (float*)d_out;

  char* ws = (char*)d_ws;
  size_t off = 0;
  auto carve = [&](size_t bytes) -> char* {
    char* p = ws + off;
    off += (bytes + 255) & ~(size_t)255;
    return p;
  };
  u16* Xb   = (u16*)carve((size_t)4194304 * 2);
  u16* Wqb  = (u16*)carve((size_t)1048576 * 2);
  u16* Wkb  = (u16*)carve((size_t)1048576 * 2);
  u16* Wvb  = (u16*)carve((size_t)1048576 * 2);
  u16* Wcpb = (u16*)carve((size_t)1048576 * 2);
  u16* Qb   = (u16*)carve((size_t)4194304 * 2);
  u16* Kb   = (u16*)carve((size_t)4194304 * 2);
  u16* Vb   = (u16*)carve((size_t)4194304 * 2);
  u16* KT   = (u16*)carve((size_t)4194304 * 2);
  u16* VT   = (u16*)carve((size_t)4194304 * 2);
  float* Sc = (float*)carve((size_t)2097152 * 4);
  u16* Scb  = (u16*)carve((size_t)2097152 * 2);
  u16* Yb   = (u16*)carve((size_t)4194304 * 2);
  float* Bm = (float*)carve((size_t)65536 * 4);
  (void)in_sizes; (void)n_in; (void)out_size; (void)ws_size;

  cvt4_kernel<<<2048, 256, 0, stream>>>(X, Xb, 4194304, Wq, Wqb, 1048576,
                                        Wk, Wkb, 1048576, Wv, Wvb, 1048576);
  bm_kernel<<<16, 256, 0, stream>>>(Ltri, Bm);
  wcp_kernel<<<1024, 256, 0, stream>>>(Wc, Bm, Wcpb);
  dim3 gg(32, 8);
  gemm_bt<u16><<<gg, 256, 0, stream>>>(Xb, Wqb, Qb, 4096, 1024, 1024);
  gemm_bt<u16><<<gg, 256, 0, stream>>>(Xb, Wkb, Kb, 4096, 1024, 1024);
  gemm_bt<u16><<<gg, 256, 0, stream>>>(Xb, Wvb, Vb, 4096, 1024, 1024);
  transpose_dl<<<dim3(1024, 2), 256, 0, stream>>>(Kb, KT, Vb, VT);
  chunk_state<<<dim3(32, 16), 256, 0, stream>>>(KT, VT, Sc);
  prefix_state<<<512, 256, 0, stream>>>(Sc, Scb);
  chunk_attn<<<dim3(32, 16), 256, 0, stream>>>(Qb, Kb, VT, Scb, Yb);
  gemm_bt<float><<<gg, 256, 0, stream>>>(Yb, Wcpb, out, 4096, 1024, 1024);
}

// Round 2
// 135.900 us; speedup vs baseline: 1.1368x; 1.1368x over previous
//
#include <hip/hip_runtime.h>

// LinearAttentionSVAR: B=2, L=2048, D=1024, H=16, d=64.
// Round 2: m97-structure GEMM (global_load_lds width=16, 2-barrier K-loop),
// fused QKV projection launch. chunk pipeline unchanged.

#define DEV static __device__ __forceinline__

typedef unsigned short u16;
typedef unsigned long long u64;
typedef __attribute__((ext_vector_type(4))) float f32x4;
typedef __attribute__((ext_vector_type(8))) short bf16x8;

DEV u16 f2bf(float f){
  union { float f; unsigned u; } v; v.f = f;
  unsigned r = v.u + 0x7FFFu + ((v.u >> 16) & 1u);
  return (u16)(r >> 16);
}

DEV void store_val(float* p, float v){ *p = v; }
DEV void store_val(u16* p, float v){ *p = f2bf(v); }

DEV void gload16(const void* g, void* l){
  __builtin_amdgcn_global_load_lds((const __attribute__((address_space(1))) void*)g,
                                   (__attribute__((address_space(3))) void*)l, 16, 0, 0);
}

// ---------------- 1. fp32 -> bf16 convert (4 regions) ----------------
__global__ __launch_bounds__(256) void cvt4_kernel(
    const float* __restrict__ s0, u16* __restrict__ d0, int n0,
    const float* __restrict__ s1, u16* __restrict__ d1, int n1,
    const float* __restrict__ s2, u16* __restrict__ d2, int n2,
    const float* __restrict__ s3, u16* __restrict__ d3, int n3)
{
  int total = (n0 + n1 + n2 + n3) >> 2;
  for(int i = blockIdx.x * blockDim.x + threadIdx.x; i < total; i += gridDim.x * blockDim.x){
    int e = i << 2;
    const float* s; u16* d;
    if(e < n0){ s = s0 + e; d = d0 + e; }
    else if(e < n0 + n1){ s = s1 + (e - n0); d = d1 + (e - n0); }
    else if(e < n0 + n1 + n2){ s = s2 + (e - n0 - n1); d = d2 + (e - n0 - n1); }
    else { s = s3 + (e - n0 - n1 - n2); d = d3 + (e - n0 - n1 - n2); }
    float4 v = *(const float4*)s;
    u64 pk = (u64)f2bf(v.x) | ((u64)f2bf(v.y) << 16) | ((u64)f2bf(v.z) << 32) | ((u64)f2bf(v.w) << 48);
    *(u64*)d = pk;
  }
}

// ---------------- 2. Bm = Lm @ Lm^T ----------------
__global__ __launch_bounds__(256) void bm_kernel(const float* __restrict__ Ltri, float* __restrict__ Bm)
{
  int h = blockIdx.x;
  __shared__ float Lm[64][65];
  const float* src = Ltri + (size_t)h * 4096;
  for(int i = threadIdx.x; i < 4096; i += 256){
    int e = i >> 6, k = i & 63;
    Lm[e][k] = (k <= e) ? src[i] : 0.f;
  }
  __syncthreads();
  float* out = Bm + (size_t)h * 4096;
  for(int i = threadIdx.x; i < 4096; i += 256){
    int e = i >> 6, dk = i & 63;
    float sum = 0.f;
    int kmax = e < dk ? e : dk;
    for(int k = 0; k <= kmax; k++) sum += Lm[e][k] * Lm[dk][k];
    out[i] = sum;
  }
}

// ---------------- 3. Wc' = fold Bm into Wc ----------------
__global__ __launch_bounds__(256) void wcp_kernel(const float* __restrict__ Wc, const float* __restrict__ Bm,
                                                  u16* __restrict__ Wcpb)
{
  int j = blockIdx.x; // 0..1023
  __shared__ float row[1024];
  for(int i = threadIdx.x; i < 1024; i += 256) row[i] = Wc[(size_t)j * 1024 + i];
  __syncthreads();
  for(int cbase = 0; cbase < 1024; cbase += 256){
    int ccol = cbase + threadIdx.x;
    int h = ccol >> 6, dk = ccol & 63;
    const float* bm = Bm + (size_t)h * 4096 + dk;
    const float* wr = &row[h * 64];
    float sum = 0.f;
#pragma unroll 8
    for(int e = 0; e < 64; e++) sum += wr[e] * bm[e * 64];
    Wcpb[(size_t)j * 1024 + ccol] = f2bf(sum);
  }
}

// ---------------- GEMM tile body: C[128,128] += A[128,K] @ W[128,K]^T ----------------
// m97 structure: global_load_lds width=16, linear LDS (elem off = t*8), 2 barriers/K-step.
template<typename OutT>
DEV void gemm128(const u16* __restrict__ A, const u16* __restrict__ W,
                 OutT* __restrict__ C, int bx, int by, int N, int K)
{
  __shared__ u16 Asm[4096];  // 128 rows x 32 cols bf16 (8 KB)
  __shared__ u16 Bsm[4096];
  const int t = threadIdx.x;
  const int wid = t >> 6, lane = t & 63;
  const int wr = wid >> 1, wc = wid & 1;
  const int lr = lane & 15, lk8 = (lane >> 4) * 8, lq = lane >> 4;
  const int srow = t >> 2, scol = (t & 3) * 8;
  const u16* Ag = A + (size_t)(bx * 128 + srow) * K + scol;
  const u16* Wg = W + (size_t)(by * 128 + srow) * K + scol;
  f32x4 acc[4][4] = {};
  for(int k0 = 0; k0 < K; k0 += 32){
    __syncthreads();
    gload16(Ag + k0, &Asm[t * 8]);
    gload16(Ag + (size_t)64 * K + k0, &Asm[2048 + t * 8]);
    gload16(Wg + k0, &Bsm[t * 8]);
    gload16(Wg + (size_t)64 * K + k0, &Bsm[2048 + t * 8]);
    __syncthreads();
    bf16x8 af[4], bfr[4];
#pragma unroll
    for(int i = 0; i < 4; i++) af[i]  = *(const bf16x8*)&Asm[(wr * 64 + i * 16 + lr) * 32 + lk8];
#pragma unroll
    for(int j = 0; j < 4; j++) bfr[j] = *(const bf16x8*)&Bsm[(wc * 64 + j * 16 + lr) * 32 + lk8];
#pragma unroll
    for(int i = 0; i < 4; i++)
#pragma unroll
      for(int j = 0; j < 4; j++)
        acc[i][j] = __builtin_amdgcn_mfma_f32_16x16x32_bf16(af[i], bfr[j], acc[i][j], 0, 0, 0);
  }
#pragma unroll
  for(int i = 0; i < 4; i++)
#pragma unroll
    for(int j = 0; j < 4; j++)
#pragma unroll
      for(int r = 0; r < 4; r++){
        int row = bx * 128 + wr * 64 + i * 16 + lq * 4 + r;
        int col = by * 128 + wc * 64 + j * 16 + lr;
        store_val(C + (size_t)row * N + col, acc[i][j][r]);
      }
}

// fused QKV projection: grid (32, 24); by 0..7 -> Q, 8..15 -> K, 16..23 -> V
__global__ __launch_bounds__(256) void qkv_gemm(
    const u16* __restrict__ Xb,
    const u16* __restrict__ Wq, const u16* __restrict__ Wk, const u16* __restrict__ Wv,
    u16* __restrict__ Q, u16* __restrict__ Ko, u16* __restrict__ V)
{
  int sel = blockIdx.y >> 3, byl = blockIdx.y & 7;
  const u16* W = sel == 0 ? Wq : sel == 1 ? Wk : Wv;
  u16* C = sel == 0 ? Q : sel == 1 ? Ko : V;
  gemm128<u16>(Xb, W, C, blockIdx.x, byl, 1024, 1024);
}

__global__ __launch_bounds__(256) void out_gemm(
    const u16* __restrict__ Yb, const u16* __restrict__ Wcpb, float* __restrict__ out)
{
  gemm128<float>(Yb, Wcpb, out, blockIdx.x, blockIdx.y, 1024, 1024);
}

// ---------------- 7. transpose K,V: [B*L][H*64] -> [B*H][64][2048] ----------------
__global__ __launch_bounds__(256) void transpose_dl(
    const u16* __restrict__ sK, u16* __restrict__ dK,
    const u16* __restrict__ sV, u16* __restrict__ dV)
{
  const u16* src = blockIdx.y ? sV : sK;
  u16* dst = blockIdx.y ? dV : dK;
  __shared__ u16 tile[64][72];
  int bh = blockIdx.x >> 5, lt = blockIdx.x & 31;
  int b = bh >> 4, h = bh & 15;
  int t = threadIdx.x;
  int r = t >> 3;          // 0..31
  int cc = (t & 7) * 8;    // 0..56
  const u16* s = src + (size_t)(b * 2048 + lt * 64) * 1024 + h * 64;
#pragma unroll
  for(int p = 0; p < 2; p++){
    int row = r + p * 32;
    int4 v = *(const int4*)(s + (size_t)row * 1024 + cc);
    *(int4*)&tile[row][cc] = v;
  }
  __syncthreads();
  u16* dptr = dst + (size_t)bh * 64 * 2048 + lt * 64;
#pragma unroll
  for(int p = 0; p < 2; p++){
    int drow = r + p * 32;   // d index
    u16 tmp[8] __attribute__((aligned(16)));
#pragma unroll
    for(int j = 0; j < 8; j++) tmp[j] = tile[cc + j][drow];
    *(int4*)(dptr + (size_t)drow * 2048 + cc) = *(const int4*)tmp;
  }
}

// ---------------- 8. per-chunk stateT[e][dk] = sum_{t in chunk} V[t,e]*K[t,dk] ----------------
__global__ __launch_bounds__(256) void chunk_state(
    const u16* __restrict__ KT, const u16* __restrict__ VT, float* __restrict__ Sc)
{
  int bh = blockIdx.x;   // 32
  int c  = blockIdx.y;   // 16
  int t = threadIdx.x, wid = t >> 6, lane = t & 63;
  int wr = wid >> 1, wc = wid & 1;
  int lr = lane & 15, lk8 = (lane >> 4) * 8, lq = lane >> 4;
  const u16* vt = VT + (size_t)bh * 64 * 2048 + (size_t)c * 128;
  const u16* kt = KT + (size_t)bh * 64 * 2048 + (size_t)c * 128;
  f32x4 acc[2][2] = {};
#pragma unroll
  for(int ks = 0; ks < 4; ks++){
    bf16x8 a[2], b[2];
#pragma unroll
    for(int i = 0; i < 2; i++) a[i] = *(const bf16x8*)(vt + (size_t)(wr * 32 + i * 16 + lr) * 2048 + ks * 32 + lk8);
#pragma unroll
    for(int j = 0; j < 2; j++) b[j] = *(const bf16x8*)(kt + (size_t)(wc * 32 + j * 16 + lr) * 2048 + ks * 32 + lk8);
#pragma unroll
    for(int i = 0; i < 2; i++)
#pragma unroll
      for(int j = 0; j < 2; j++)
        acc[i][j] = __builtin_amdgcn_mfma_f32_16x16x32_bf16(a[i], b[j], acc[i][j], 0, 0, 0);
  }
  float* out = Sc + ((size_t)bh * 16 + c) * 4096;
#pragma unroll
  for(int i = 0; i < 2; i++)
#pragma unroll
    for(int j = 0; j < 2; j++)
#pragma unroll
      for(int r = 0; r < 4; r++){
        int e = wr * 32 + i * 16 + lq * 4 + r, dk = wc * 32 + j * 16 + lr;
        out[e * 64 + dk] = acc[i][j][r];
      }
}

// ---------------- 9. exclusive prefix over chunks, fp32 -> bf16 ----------------
__global__ __launch_bounds__(256) void prefix_state(const float* __restrict__ Sc, u16* __restrict__ Scb)
{
  int bh = blockIdx.x >> 4, part = blockIdx.x & 15;
  int e = part * 256 + threadIdx.x; // 0..4095
  const float* s = Sc + (size_t)bh * 16 * 4096 + e;
  u16* d = Scb + (size_t)bh * 16 * 4096 + e;
  float run = 0.f;
  for(int c = 0; c < 16; c++){
    float v = s[(size_t)c * 4096];
    d[(size_t)c * 4096] = f2bf(run);
    run += v;
  }
}

// ---------------- 10. per-chunk attention: Y = Q@stateT^T + tril(Q@K^T)@V ----------------
__global__ __launch_bounds__(256) void chunk_attn(
    const u16* __restrict__ Q, const u16* __restrict__ Kmat,
    const u16* __restrict__ VT, const u16* __restrict__ Scb, u16* __restrict__ Y)
{
  int bh = blockIdx.x, c = blockIdx.y;
  int b = bh >> 4, h = bh & 15;
  int t = threadIdx.x, wid = t >> 6, lane = t & 63;
  int lr = lane & 15, lk8 = (lane >> 4) * 8, lq = lane >> 4;
  __shared__ u16 S[128 * 128];  // bf16 scores, XOR-swizzled rows
#pragma unroll
  for(int i = 0; i < 16; i++) ((u64*)S)[t + i * 256] = 0ULL;
  __syncthreads();
  const u16* qg = Q    + (size_t)(b * 2048 + c * 128) * 1024 + h * 64;
  const u16* kg = Kmat + (size_t)(b * 2048 + c * 128) * 1024 + h * 64;
  // ---- phase 1: S = tril(Q @ K^T), K-dim = 64 ----
#pragma unroll
  for(int mi = 0; mi < 2; mi++){
    int mf = wid + mi * 4;        // m-frag index 0..7
    int Rm = mf * 16;
    bf16x8 a[2];
#pragma unroll
    for(int ks = 0; ks < 2; ks++) a[ks] = *(const bf16x8*)(qg + (size_t)(Rm + lr) * 1024 + ks * 32 + lk8);
    for(int nf = 0; nf <= mf; nf++){
      f32x4 acc = {};
#pragma unroll
      for(int ks = 0; ks < 2; ks++){
        bf16x8 bb = *(const bf16x8*)(kg + (size_t)(nf * 16 + lr) * 1024 + ks * 32 + lk8);
        acc = __builtin_amdgcn_mfma_f32_16x16x32_bf16(a[ks], bb, acc, 0, 0, 0);
      }
#pragma unroll
      for(int r = 0; r < 4; r++){
        int row = lq * 4 + r, col = lr;
        float v = acc[r];
        if(nf == mf && col > row) v = 0.f;  // causal mask on diagonal frag
        int grow = Rm + row, gcol = nf * 16 + col;
        int off = (grow * 128 + gcol) * 2;
        off ^= ((grow & 7) << 4);
        *(u16*)((char*)S + off) = f2bf(v);
      }
    }
  }
  __syncthreads();
  // ---- phase 2: Y = Q @ stateT^T  +  S @ V ----
  const u16* scb = Scb + ((size_t)bh * 16 + c) * 4096;
  const u16* vt  = VT + (size_t)bh * 64 * 2048 + (size_t)c * 128;
  u16* yg = Y + (size_t)(b * 2048 + c * 128) * 1024 + h * 64;
#pragma unroll
  for(int mi = 0; mi < 2; mi++){
    int mf = wid + mi * 4;
    int Rm = mf * 16;
    f32x4 acc[4] = {};
    bf16x8 a[2];
#pragma unroll
    for(int ks = 0; ks < 2; ks++) a[ks] = *(const bf16x8*)(qg + (size_t)(Rm + lr) * 1024 + ks * 32 + lk8);
#pragma unroll
    for(int nf = 0; nf < 4; nf++){
#pragma unroll
      for(int ks = 0; ks < 2; ks++){
        bf16x8 bb = *(const bf16x8*)(scb + (nf * 16 + lr) * 64 + ks * 32 + lk8);
        acc[nf] = __builtin_amdgcn_mfma_f32_16x16x32_bf16(a[ks], bb, acc[nf], 0, 0, 0);
      }
    }
    int ksmax = mf >> 1;
    for(int ks = 0; ks <= ksmax; ks++){
      int row = Rm + lr;
      int off = (row * 128 + ks * 32 + lk8) * 2;
      off ^= ((row & 7) << 4);
      bf16x8 af = *(const bf16x8*)((char*)S + off);
#pragma unroll
      for(int nf = 0; nf < 4; nf++){
        bf16x8 bb = *(const bf16x8*)(vt + (size_t)(nf * 16 + lr) * 2048 + ks * 32 + lk8);
        acc[nf] = __builtin_amdgcn_mfma_f32_16x16x32_bf16(af, bb, acc[nf], 0, 0, 0);
      }
    }
#pragma unroll
    for(int nf = 0; nf < 4; nf++)
#pragma unroll
      for(int r = 0; r < 4; r++){
        int grow = Rm + lq * 4 + r, gcol = nf * 16 + lr;
        yg[(size_t)grow * 1024 + gcol] = f2bf(acc[nf][r]);
      }
  }
}

// ---------------- launch ----------------
extern "C" void kernel_launch(void* const* d_in, const int* in_sizes, int n_in,
                              void* d_out, int out_size, void* d_ws, size_t ws_size,
                              hipStream_t stream)
{
  const float* X    = (const float*)d_in[0];
  const float* Wq   = (const float*)d_in[1];
  const float* Wk   = (const float*)d_in[2];
  const float* Wv   = (const float*)d_in[3];
  const float* Wc   = (const float*)d_in[4];
  const float* Ltri = (const float*)d_in[5];
  float* out = (float*)d_out;

  char* ws = (char*)d_ws;
  size_t off = 0;
  auto carve = [&](size_t bytes) -> char* {
    char* p = ws + off;
    off += (bytes + 255) & ~(size_t)255;
    return p;
  };
  u16* Xb   = (u16*)carve((size_t)4194304 * 2);
  u16* Wqb  = (u16*)carve((size_t)1048576 * 2);
  u16* Wkb  = (u16*)carve((size_t)1048576 * 2);
  u16* Wvb  = (u16*)carve((size_t)1048576 * 2);
  u16* Wcpb = (u16*)carve((size_t)1048576 * 2);
  u16* Qb   = (u16*)carve((size_t)4194304 * 2);
  u16* Kb   = (u16*)carve((size_t)4194304 * 2);
  u16* Vb   = (u16*)carve((size_t)4194304 * 2);
  u16* KT   = (u16*)carve((size_t)4194304 * 2);
  u16* VT   = (u16*)carve((size_t)4194304 * 2);
  float* Sc = (float*)carve((size_t)2097152 * 4);
  u16* Scb  = (u16*)carve((size_t)2097152 * 2);
  u16* Yb   = (u16*)carve((size_t)4194304 * 2);
  float* Bm = (float*)carve((size_t)65536 * 4);
  (void)in_sizes; (void)n_in; (void)out_size; (void)ws_size;

  cvt4_kernel<<<2048, 256, 0, stream>>>(X, Xb, 4194304, Wq, Wqb, 1048576,
                                        Wk, Wkb, 1048576, Wv, Wvb, 1048576);
  bm_kernel<<<16, 256, 0, stream>>>(Ltri, Bm);
  wcp_kernel<<<1024, 256, 0, stream>>>(Wc, Bm, Wcpb);
  qkv_gemm<<<dim3(32, 24), 256, 0, stream>>>(Xb, Wqb, Wkb, Wvb, Qb, Kb, Vb);
  transpose_dl<<<dim3(1024, 2), 256, 0, stream>>>(Kb, KT, Vb, VT);
  chunk_state<<<dim3(32, 16), 256, 0, stream>>>(KT, VT, Sc);
  prefix_state<<<512, 256, 0, stream>>>(Sc, Scb);
  chunk_attn<<<dim3(32, 16), 256, 0, stream>>>(Qb, Kb, VT, Scb, Yb);
  out_gemm<<<dim3(32, 8), 256, 0, stream>>>(Yb, Wcpb, out);
}

// Round 3
// 121.949 us; speedup vs baseline: 1.2669x; 1.1144x over previous
//
#include <hip/hip_runtime.h>

// LinearAttentionSVAR: B=2, L=2048, D=1024, H=16, d=64.
// Round 3:
//  - gemm128_p2: depth-2 prefetch (3 LDS bufs), counted vmcnt(4), one raw
//    s_barrier per K-step (never vmcnt(0) mid-loop). Targets out_gemm's
//    1-block/CU regime where the compiler's pre-barrier drain is fully exposed.
//  - prep: cvt(X,Wq,Wk,Wv) + (Bm=LmLm^T folded into Wc') in one launch.
//  - state_chunk: transpose+chunk_state fused; KT buffer eliminated.
//  - prefix: float4-vectorized.
//  - chunk_attn: barrier-free (each wave reads only self-written S rows).
// 6 launches total.

#define DEV static __device__ __forceinline__

typedef unsigned short u16;
typedef unsigned long long u64;
typedef __attribute__((ext_vector_type(4))) float f32x4;
typedef __attribute__((ext_vector_type(8))) short bf16x8;

DEV u16 f2bf(float f){
  union { float f; unsigned u; } v; v.f = f;
  unsigned r = v.u + 0x7FFFu + ((v.u >> 16) & 1u);
  return (u16)(r >> 16);
}

DEV void store_val(float* p, float v){ *p = v; }
DEV void store_val(u16* p, float v){ *p = f2bf(v); }

DEV void gload16(const void* g, void* l){
  __builtin_amdgcn_global_load_lds((const __attribute__((address_space(1))) void*)g,
                                   (__attribute__((address_space(3))) void*)l, 16, 0, 0);
}

// ---------------- 1. prep: bf16 converts + Wc' fold ----------------
// blocks 0..1023: (h=bx>>6, part=bx&63) compute Bm_h in LDS, emit 16 rows of Wc'.
// blocks 1024..3071: grid-stride bf16 convert of X, Wq, Wk, Wv.
__global__ __launch_bounds__(256) void prep_kernel(
    const float* __restrict__ X, u16* __restrict__ Xb,
    const float* __restrict__ Wq, u16* __restrict__ Wqb,
    const float* __restrict__ Wk, u16* __restrict__ Wkb,
    const float* __restrict__ Wv, u16* __restrict__ Wvb,
    const float* __restrict__ Wc, const float* __restrict__ Ltri,
    u16* __restrict__ Wcpb)
{
  __shared__ float Lm[64][65];
  __shared__ float Bm[64][64];
  const int bx = blockIdx.x, tid = threadIdx.x;
  if(bx < 1024){
    int h = bx >> 6, part = bx & 63;
    const float* src = Ltri + (size_t)h * 4096;
    for(int i = tid; i < 4096; i += 256){
      int e = i >> 6, k = i & 63;
      Lm[e][k] = (k <= e) ? src[i] : 0.f;
    }
    __syncthreads();
    for(int i = tid; i < 4096; i += 256){
      int e = i >> 6, dk = i & 63;
      float sum = 0.f;
      int kmax = e < dk ? e : dk;
      for(int k = 0; k <= kmax; k++) sum += Lm[e][k] * Lm[dk][k];
      Bm[e][dk] = sum;
    }
    __syncthreads();
    for(int o = 0; o < 4; o++){
      int idx = o * 256 + tid;                  // 0..1023
      int jr = part * 16 + (idx >> 6), dk = idx & 63;
      const float* wr_ = Wc + (size_t)jr * 1024 + h * 64;
      float sum = 0.f;
#pragma unroll 8
      for(int e = 0; e < 64; e++) sum += wr_[e] * Bm[e][dk];
      Wcpb[(size_t)jr * 1024 + h * 64 + dk] = f2bf(sum);
    }
  } else {
    const int n0 = 4194304, n1 = 1048576, n2 = 1048576, n3 = 1048576;
    int total = (n0 + n1 + n2 + n3) >> 2;
    for(int i = (bx - 1024) * 256 + tid; i < total; i += 2048 * 256){
      int e = i << 2;
      const float* s; u16* d;
      if(e < n0){ s = X + e; d = Xb + e; }
      else if(e < n0 + n1){ s = Wq + (e - n0); d = Wqb + (e - n0); }
      else if(e < n0 + n1 + n2){ s = Wk + (e - n0 - n1); d = Wkb + (e - n0 - n1); }
      else { s = Wv + (e - n0 - n1 - n2); d = Wvb + (e - n0 - n1 - n2); }
      float4 v = *(const float4*)s;
      u64 pk = (u64)f2bf(v.x) | ((u64)f2bf(v.y) << 16) | ((u64)f2bf(v.z) << 32) | ((u64)f2bf(v.w) << 48);
      *(u64*)d = pk;
    }
  }
}

// ---------------- GEMM tile body, depth-2 prefetch ----------------
// C[128,128] = A[128,K] @ W[128,K]^T. 3 LDS buffers, stage tile t+2 each iter,
// one raw s_barrier + counted vmcnt per K-step.
template<typename OutT>
DEV void gemm128_p2(const u16* __restrict__ A, const u16* __restrict__ W,
                    OutT* __restrict__ C, int bx, int by, int N, int K)
{
  __shared__ u16 L[3][8192];   // per buf: A tile [0..4095], B tile [4096..8191]
  const int tid = threadIdx.x;
  const int wid = tid >> 6, lane = tid & 63;
  const int wr = wid >> 1, wc = wid & 1;
  const int lr = lane & 15, lk8 = (lane >> 4) * 8, lq = lane >> 4;
  const int srow = tid >> 2, scol = (tid & 3) * 8;
  const u16* Ag = A + (size_t)(bx * 128 + srow) * K + scol;
  const u16* Wg = W + (size_t)(by * 128 + srow) * K + scol;

  auto stagef = [&](int kt, int buf){
    const u16* a = Ag + kt * 32;
    const u16* w = Wg + kt * 32;
    gload16(a,                    &L[buf][tid * 8]);
    gload16(a + (size_t)64 * K,   &L[buf][2048 + tid * 8]);
    gload16(w,                    &L[buf][4096 + tid * 8]);
    gload16(w + (size_t)64 * K,   &L[buf][6144 + tid * 8]);
  };

  const int nt = K >> 5;
  f32x4 acc[4][4] = {};
  stagef(0, 0);
  stagef(1, 1);
  int cur = 0;
  for(int t = 0; t < nt; t++){
    if(t < nt - 1) asm volatile("s_waitcnt vmcnt(4)" ::: "memory");
    else           asm volatile("s_waitcnt vmcnt(0)" ::: "memory");
    __builtin_amdgcn_s_barrier();
    __builtin_amdgcn_sched_barrier(0);
    if(t + 2 < nt){
      int n2 = cur >= 1 ? cur - 1 : cur + 2;   // (t+2)%3
      stagef(t + 2, n2);
    }
    bf16x8 af[4], bfr[4];
#pragma unroll
    for(int i = 0; i < 4; i++) af[i]  = *(const bf16x8*)&L[cur][(wr * 64 + i * 16 + lr) * 32 + lk8];
#pragma unroll
    for(int j = 0; j < 4; j++) bfr[j] = *(const bf16x8*)&L[cur][4096 + (wc * 64 + j * 16 + lr) * 32 + lk8];
#pragma unroll
    for(int i = 0; i < 4; i++)
#pragma unroll
      for(int j = 0; j < 4; j++)
        acc[i][j] = __builtin_amdgcn_mfma_f32_16x16x32_bf16(af[i], bfr[j], acc[i][j], 0, 0, 0);
    cur = cur == 2 ? 0 : cur + 1;
  }
#pragma unroll
  for(int i = 0; i < 4; i++)
#pragma unroll
    for(int j = 0; j < 4; j++)
#pragma unroll
      for(int r = 0; r < 4; r++){
        int row = bx * 128 + wr * 64 + i * 16 + lq * 4 + r;
        int col = by * 128 + wc * 64 + j * 16 + lr;
        store_val(C + (size_t)row * N + col, acc[i][j][r]);
      }
}

// fused QKV projection: grid (32, 24); by 0..7 -> Q, 8..15 -> K, 16..23 -> V
__global__ __launch_bounds__(256) void qkv_gemm(
    const u16* __restrict__ Xb,
    const u16* __restrict__ Wq, const u16* __restrict__ Wk, const u16* __restrict__ Wv,
    u16* __restrict__ Q, u16* __restrict__ Ko, u16* __restrict__ V)
{
  int sel = blockIdx.y >> 3, byl = blockIdx.y & 7;
  const u16* W = sel == 0 ? Wq : sel == 1 ? Wk : Wv;
  u16* C = sel == 0 ? Q : sel == 1 ? Ko : V;
  gemm128_p2<u16>(Xb, W, C, blockIdx.x, byl, 1024, 1024);
}

__global__ __launch_bounds__(256) void out_gemm(
    const u16* __restrict__ Yb, const u16* __restrict__ Wcpb, float* __restrict__ out)
{
  gemm128_p2<float>(Yb, Wcpb, out, blockIdx.x, blockIdx.y, 1024, 1024);
}

// ---------------- state_chunk: fused K/V transpose + per-chunk state ----------------
// block (bh, c): loads K,V chunk [128 x 64] row-major, writes VT[bh][d][L] slice,
// computes stateT[e][dk] = sum_t V[t,e] K[t,dk] via MFMA (LDS column gathers).
__global__ __launch_bounds__(256) void state_chunk(
    const u16* __restrict__ Kb, const u16* __restrict__ Vb,
    u16* __restrict__ VT, float* __restrict__ Sc)
{
  int bh = blockIdx.x, c = blockIdx.y;
  int b = bh >> 4, h = bh & 15;
  int tid = threadIdx.x;
  __shared__ u16 Kt[128][72];
  __shared__ u16 Vt[128][72];
  int rr = tid >> 3;            // 0..31
  int cc = (tid & 7) * 8;       // 0..56
  const u16* kg = Kb + (size_t)(b * 2048 + c * 128) * 1024 + h * 64;
  const u16* vg = Vb + (size_t)(b * 2048 + c * 128) * 1024 + h * 64;
#pragma unroll
  for(int p = 0; p < 4; p++){
    int row = rr + p * 32;
    *(int4*)&Kt[row][cc] = *(const int4*)(kg + (size_t)row * 1024 + cc);
    *(int4*)&Vt[row][cc] = *(const int4*)(vg + (size_t)row * 1024 + cc);
  }
  __syncthreads();
  // (a) VT write: thread -> (d = tid>>2, 32 t's)
  {
    int d = tid >> 2, tseg = (tid & 3) * 32;
    u16* vto = VT + (size_t)bh * 64 * 2048 + (size_t)d * 2048 + c * 128 + tseg;
#pragma unroll
    for(int j = 0; j < 32; j += 8){
      u16 tmp[8] __attribute__((aligned(16)));
#pragma unroll
      for(int q = 0; q < 8; q++) tmp[q] = Vt[tseg + j + q][d];
      *(int4*)(vto + j) = *(const int4*)tmp;
    }
  }
  // (b) state MFMA
  int wid = tid >> 6, lane = tid & 63;
  int wr = wid >> 1, wc = wid & 1;
  int lr = lane & 15, lk8 = (lane >> 4) * 8, lq = lane >> 4;
  f32x4 acc[2][2] = {};
#pragma unroll
  for(int ks = 0; ks < 4; ks++){
    bf16x8 a[2], bb[2];
#pragma unroll
    for(int i = 0; i < 2; i++){
      u16 tmp[8] __attribute__((aligned(16)));
      int e = wr * 32 + i * 16 + lr;
#pragma unroll
      for(int q = 0; q < 8; q++) tmp[q] = Vt[ks * 32 + lk8 + q][e];
      a[i] = *(const bf16x8*)tmp;
    }
#pragma unroll
    for(int j = 0; j < 2; j++){
      u16 tmp[8] __attribute__((aligned(16)));
      int dk = wc * 32 + j * 16 + lr;
#pragma unroll
      for(int q = 0; q < 8; q++) tmp[q] = Kt[ks * 32 + lk8 + q][dk];
      bb[j] = *(const bf16x8*)tmp;
    }
#pragma unroll
    for(int i = 0; i < 2; i++)
#pragma unroll
      for(int j = 0; j < 2; j++)
        acc[i][j] = __builtin_amdgcn_mfma_f32_16x16x32_bf16(a[i], bb[j], acc[i][j], 0, 0, 0);
  }
  float* out = Sc + ((size_t)bh * 16 + c) * 4096;
#pragma unroll
  for(int i = 0; i < 2; i++)
#pragma unroll
    for(int j = 0; j < 2; j++)
#pragma unroll
      for(int r = 0; r < 4; r++){
        int e = wr * 32 + i * 16 + lq * 4 + r, dk = wc * 32 + j * 16 + lr;
        out[e * 64 + dk] = acc[i][j][r];
      }
}

// ---------------- prefix: exclusive chunk prefix, float4-vectorized ----------------
__global__ __launch_bounds__(256) void prefix_state(const float* __restrict__ Sc, u16* __restrict__ Scb)
{
  int bh = blockIdx.x >> 2, part = blockIdx.x & 3;
  int e4 = part * 256 + threadIdx.x;   // float4 index 0..1023
  const float4* s = (const float4*)(Sc + (size_t)bh * 65536) + e4;
  u16* d = Scb + (size_t)bh * 65536 + e4 * 4;
  float4 run = {0.f, 0.f, 0.f, 0.f};
  for(int c = 0; c < 16; c++){
    float4 v = s[(size_t)c * 1024];
    u64 pk = (u64)f2bf(run.x) | ((u64)f2bf(run.y) << 16) | ((u64)f2bf(run.z) << 32) | ((u64)f2bf(run.w) << 48);
    *(u64*)(d + (size_t)c * 4096) = pk;
    run.x += v.x; run.y += v.y; run.z += v.z; run.w += v.w;
  }
}

// ---------------- chunk_attn: Y = Q@stateT^T + tril(Q@K^T)@V, barrier-free ----------------
__global__ __launch_bounds__(256) void chunk_attn(
    const u16* __restrict__ Q, const u16* __restrict__ Kmat,
    const u16* __restrict__ VT, const u16* __restrict__ Scb, u16* __restrict__ Y)
{
  int bh = blockIdx.x, c = blockIdx.y;
  int b = bh >> 4, h = bh & 15;
  int t = threadIdx.x, wid = t >> 6, lane = t & 63;
  int lr = lane & 15, lk8 = (lane >> 4) * 8, lq = lane >> 4;
  __shared__ u16 S[128 * 128];  // bf16 scores, XOR-swizzled rows; each wave touches only its own rows
  const u16* qg = Q    + (size_t)(b * 2048 + c * 128) * 1024 + h * 64;
  const u16* kg = Kmat + (size_t)(b * 2048 + c * 128) * 1024 + h * 64;
  const u16* scb = Scb + ((size_t)bh * 16 + c) * 4096;
  const u16* vt  = VT + (size_t)bh * 64 * 2048 + (size_t)c * 128;
  u16* yg = Y + (size_t)(b * 2048 + c * 128) * 1024 + h * 64;
#pragma unroll
  for(int mi = 0; mi < 2; mi++){
    int mf = wid + mi * 4;        // m-frag block 0..7 (this wave's rows Rm..Rm+15)
    int Rm = mf * 16;
    // zero the strict-upper pad this wave will read (even mf only: cols Rm+16..Rm+31)
    if((mf & 1) == 0){
      int zr = Rm + (lane >> 2), zc = Rm + 16 + (lane & 3) * 4;
      int zoff = ((zr * 128 + zc) * 2) ^ ((zr & 7) << 4);
      *(u64*)((char*)S + zoff) = 0ULL;
    }
    bf16x8 a[2];
#pragma unroll
    for(int ks = 0; ks < 2; ks++) a[ks] = *(const bf16x8*)(qg + (size_t)(Rm + lr) * 1024 + ks * 32 + lk8);
    // phase 1: S rows Rm..Rm+15 = tril(Q K^T)
    for(int nf = 0; nf <= mf; nf++){
      f32x4 acc = {};
#pragma unroll
      for(int ks = 0; ks < 2; ks++){
        bf16x8 bb = *(const bf16x8*)(kg + (size_t)(nf * 16 + lr) * 1024 + ks * 32 + lk8);
        acc = __builtin_amdgcn_mfma_f32_16x16x32_bf16(a[ks], bb, acc, 0, 0, 0);
      }
#pragma unroll
      for(int r = 0; r < 4; r++){
        int row = lq * 4 + r, col = lr;
        float v = acc[r];
        if(nf == mf && col > row) v = 0.f;
        int grow = Rm + row, gcol = nf * 16 + col;
        int off = ((grow * 128 + gcol) * 2) ^ ((grow & 7) << 4);
        *(u16*)((char*)S + off) = f2bf(v);
      }
    }
    // phase 2: Y rows = Q @ stateT^T + S @ V (reads only self-written/zeroed S)
    f32x4 acc2[4] = {};
#pragma unroll
    for(int nf = 0; nf < 4; nf++){
#pragma unroll
      for(int ks = 0; ks < 2; ks++){
        bf16x8 bb = *(const bf16x8*)(scb + (nf * 16 + lr) * 64 + ks * 32 + lk8);
        acc2[nf] = __builtin_amdgcn_mfma_f32_16x16x32_bf16(a[ks], bb, acc2[nf], 0, 0, 0);
      }
    }
    int ksmax = mf >> 1;
    for(int ks = 0; ks <= ksmax; ks++){
      int row = Rm + lr;
      int off = ((row * 128 + ks * 32 + lk8) * 2) ^ ((row & 7) << 4);
      bf16x8 af = *(const bf16x8*)((char*)S + off);
#pragma unroll
      for(int nf = 0; nf < 4; nf++){
        bf16x8 bb = *(const bf16x8*)(vt + (size_t)(nf * 16 + lr) * 2048 + ks * 32 + lk8);
        acc2[nf] = __builtin_amdgcn_mfma_f32_16x16x32_bf16(af, bb, acc2[nf], 0, 0, 0);
      }
    }
#pragma unroll
    for(int nf = 0; nf < 4; nf++)
#pragma unroll
      for(int r = 0; r < 4; r++){
        int grow = Rm + lq * 4 + r, gcol = nf * 16 + lr;
        yg[(size_t)grow * 1024 + gcol] = f2bf(acc2[nf][r]);
      }
  }
}

// ---------------- launch ----------------
extern "C" void kernel_launch(void* const* d_in, const int* in_sizes, int n_in,
                              void* d_out, int out_size, void* d_ws, size_t ws_size,
                              hipStream_t stream)
{
  const float* X    = (const float*)d_in[0];
  const float* Wq   = (const float*)d_in[1];
  const float* Wk   = (const float*)d_in[2];
  const float* Wv   = (const float*)d_in[3];
  const float* Wc   = (const float*)d_in[4];
  const float* Ltri = (const float*)d_in[5];
  float* out = (float*)d_out;

  char* ws = (char*)d_ws;
  size_t off = 0;
  auto carve = [&](size_t bytes) -> char* {
    char* p = ws + off;
    off += (bytes + 255) & ~(size_t)255;
    return p;
  };
  u16* Xb   = (u16*)carve((size_t)4194304 * 2);
  u16* Wqb  = (u16*)carve((size_t)1048576 * 2);
  u16* Wkb  = (u16*)carve((size_t)1048576 * 2);
  u16* Wvb  = (u16*)carve((size_t)1048576 * 2);
  u16* Wcpb = (u16*)carve((size_t)1048576 * 2);
  u16* Qb   = (u16*)carve((size_t)4194304 * 2);
  u16* Kb   = (u16*)carve((size_t)4194304 * 2);
  u16* Vb   = (u16*)carve((size_t)4194304 * 2);
  u16* VT   = (u16*)carve((size_t)4194304 * 2);
  float* Sc = (float*)carve((size_t)2097152 * 4);
  u16* Scb  = (u16*)carve((size_t)2097152 * 2);
  u16* Yb   = (u16*)carve((size_t)4194304 * 2);
  (void)in_sizes; (void)n_in; (void)out_size; (void)ws_size;

  prep_kernel<<<3072, 256, 0, stream>>>(X, Xb, Wq, Wqb, Wk, Wkb, Wv, Wvb, Wc, Ltri, Wcpb);
  qkv_gemm<<<dim3(32, 24), 256, 0, stream>>>(Xb, Wqb, Wkb, Wvb, Qb, Kb, Vb);
  state_chunk<<<dim3(32, 16), 256, 0, stream>>>(Kb, Vb, VT, Sc);
  prefix_state<<<128, 256, 0, stream>>>(Sc, Scb);
  chunk_attn<<<dim3(32, 16), 256, 0, stream>>>(Qb, Kb, VT, Scb, Yb);
  out_gemm<<<dim3(32, 8), 256, 0, stream>>>(Yb, Wcpb, out);
}

// Round 4
// 106.758 us; speedup vs baseline: 1.4471x; 1.1423x over previous
//
#include <hip/hip_runtime.h>

// LinearAttentionSVAR: B=2, L=2048, D=1024, H=16, d=64.
// Round 4: kill the 45µs scalar Bm/Wc' fold.
//  - prep: blocks 0..15 compute Bm_h ONCE per head -> bf16 global; blocks
//    16..2063 convert X,Wq,Wk,Wv,Wc -> bf16 (BW-bound, ~8µs).
//  - Wc' fold = per-head MFMA GEMM (Bm symmetric => Wc'_h = Wc_h @ Bm_h^T),
//    merged into qkv_gemm grid (by=24..27). No LDS, global->reg, K=64.
//  - gemm128_p2 (depth-2 prefetch, counted vmcnt), state_chunk, prefix,
//    chunk_attn unchanged. 6 launches.

#define DEV static __device__ __forceinline__

typedef unsigned short u16;
typedef unsigned long long u64;
typedef __attribute__((ext_vector_type(4))) float f32x4;
typedef __attribute__((ext_vector_type(8))) short bf16x8;

DEV u16 f2bf(float f){
  union { float f; unsigned u; } v; v.f = f;
  unsigned r = v.u + 0x7FFFu + ((v.u >> 16) & 1u);
  return (u16)(r >> 16);
}

DEV void store_val(float* p, float v){ *p = v; }
DEV void store_val(u16* p, float v){ *p = f2bf(v); }

DEV void gload16(const void* g, void* l){
  __builtin_amdgcn_global_load_lds((const __attribute__((address_space(1))) void*)g,
                                   (__attribute__((address_space(3))) void*)l, 16, 0, 0);
}

// ---------------- 1. prep: bf16 converts + per-head Bm ----------------
// blocks 0..15: h = bx; Bm_h = tril(Ltri_h) @ tril(Ltri_h)^T -> bf16 Bmb.
// blocks 16..2063: grid-stride bf16 convert of X, Wq, Wk, Wv, Wc.
__global__ __launch_bounds__(256) void prep_kernel(
    const float* __restrict__ X, u16* __restrict__ Xb,
    const float* __restrict__ Wq, u16* __restrict__ Wqb,
    const float* __restrict__ Wk, u16* __restrict__ Wkb,
    const float* __restrict__ Wv, u16* __restrict__ Wvb,
    const float* __restrict__ Wc, u16* __restrict__ Wcb,
    const float* __restrict__ Ltri, u16* __restrict__ Bmb)
{
  const int bx = blockIdx.x, tid = threadIdx.x;
  if(bx < 16){
    __shared__ float Lm[64][65];
    int h = bx;
    const float* src = Ltri + (size_t)h * 4096;
    for(int i = tid; i < 4096; i += 256){
      int e = i >> 6, k = i & 63;
      Lm[e][k] = (k <= e) ? src[i] : 0.f;
    }
    __syncthreads();
    u16* out = Bmb + (size_t)h * 4096;
    for(int i = tid; i < 4096; i += 256){
      int e = i >> 6, dk = i & 63;
      float sum = 0.f;
      int kmax = e < dk ? e : dk;
      for(int k = 0; k <= kmax; k++) sum += Lm[e][k] * Lm[dk][k];
      out[i] = f2bf(sum);
    }
  } else {
    const int n0 = 4194304, n1 = 1048576, n2 = 1048576, n3 = 1048576, n4 = 1048576;
    int total = (n0 + n1 + n2 + n3 + n4) >> 2;
    for(int i = (bx - 16) * 256 + tid; i < total; i += 2048 * 256){
      int e = i << 2;
      const float* s; u16* d;
      if(e < n0){ s = X + e; d = Xb + e; }
      else if(e < n0 + n1){ s = Wq + (e - n0); d = Wqb + (e - n0); }
      else if(e < n0 + n1 + n2){ s = Wk + (e - n0 - n1); d = Wkb + (e - n0 - n1); }
      else if(e < n0 + n1 + n2 + n3){ s = Wv + (e - n0 - n1 - n2); d = Wvb + (e - n0 - n1 - n2); }
      else { s = Wc + (e - n0 - n1 - n2 - n3); d = Wcb + (e - n0 - n1 - n2 - n3); }
      float4 v = *(const float4*)s;
      u64 pk = (u64)f2bf(v.x) | ((u64)f2bf(v.y) << 16) | ((u64)f2bf(v.z) << 32) | ((u64)f2bf(v.w) << 48);
      *(u64*)d = pk;
    }
  }
}

// ---------------- GEMM tile body, depth-2 prefetch ----------------
template<typename OutT>
DEV void gemm128_p2(const u16* __restrict__ A, const u16* __restrict__ W,
                    OutT* __restrict__ C, int bx, int by, int N, int K)
{
  __shared__ u16 L[3][8192];   // per buf: A tile [0..4095], B tile [4096..8191]
  const int tid = threadIdx.x;
  const int wid = tid >> 6, lane = tid & 63;
  const int wr = wid >> 1, wc = wid & 1;
  const int lr = lane & 15, lk8 = (lane >> 4) * 8, lq = lane >> 4;
  const int srow = tid >> 2, scol = (tid & 3) * 8;
  const u16* Ag = A + (size_t)(bx * 128 + srow) * K + scol;
  const u16* Wg = W + (size_t)(by * 128 + srow) * K + scol;

  auto stagef = [&](int kt, int buf){
    const u16* a = Ag + kt * 32;
    const u16* w = Wg + kt * 32;
    gload16(a,                    &L[buf][tid * 8]);
    gload16(a + (size_t)64 * K,   &L[buf][2048 + tid * 8]);
    gload16(w,                    &L[buf][4096 + tid * 8]);
    gload16(w + (size_t)64 * K,   &L[buf][6144 + tid * 8]);
  };

  const int nt = K >> 5;
  f32x4 acc[4][4] = {};
  stagef(0, 0);
  stagef(1, 1);
  int cur = 0;
  for(int t = 0; t < nt; t++){
    if(t < nt - 1) asm volatile("s_waitcnt vmcnt(4)" ::: "memory");
    else           asm volatile("s_waitcnt vmcnt(0)" ::: "memory");
    __builtin_amdgcn_s_barrier();
    __builtin_amdgcn_sched_barrier(0);
    if(t + 2 < nt){
      int n2 = cur >= 1 ? cur - 1 : cur + 2;   // (t+2)%3
      stagef(t + 2, n2);
    }
    bf16x8 af[4], bfr[4];
#pragma unroll
    for(int i = 0; i < 4; i++) af[i]  = *(const bf16x8*)&L[cur][(wr * 64 + i * 16 + lr) * 32 + lk8];
#pragma unroll
    for(int j = 0; j < 4; j++) bfr[j] = *(const bf16x8*)&L[cur][4096 + (wc * 64 + j * 16 + lr) * 32 + lk8];
#pragma unroll
    for(int i = 0; i < 4; i++)
#pragma unroll
      for(int j = 0; j < 4; j++)
        acc[i][j] = __builtin_amdgcn_mfma_f32_16x16x32_bf16(af[i], bfr[j], acc[i][j], 0, 0, 0);
    cur = cur == 2 ? 0 : cur + 1;
  }
#pragma unroll
  for(int i = 0; i < 4; i++)
#pragma unroll
    for(int j = 0; j < 4; j++)
#pragma unroll
      for(int r = 0; r < 4; r++){
        int row = bx * 128 + wr * 64 + i * 16 + lq * 4 + r;
        int col = by * 128 + wc * 64 + j * 16 + lr;
        store_val(C + (size_t)row * N + col, acc[i][j][r]);
      }
}

// fused QKV projection + Wc' fold.
// by 0..7 -> Q, 8..15 -> K, 16..23 -> V; by 24..27 -> Wc' fold (per-head MFMA).
__global__ __launch_bounds__(256) void qkv_gemm(
    const u16* __restrict__ Xb,
    const u16* __restrict__ Wq, const u16* __restrict__ Wk, const u16* __restrict__ Wv,
    u16* __restrict__ Q, u16* __restrict__ Ko, u16* __restrict__ V,
    const u16* __restrict__ Wcb, const u16* __restrict__ Bmb, u16* __restrict__ Wcpb)
{
  if(blockIdx.y >= 24){
    // Wc'_h[128 rows x 64 cols] = Wc_h @ Bm_h^T (Bm symmetric), K = 64.
    int rt = blockIdx.x & 7, h = (blockIdx.x >> 3) + ((blockIdx.y - 24) << 2);
    int wid = threadIdx.x >> 6, lane = threadIdx.x & 63;
    int lr = lane & 15, lk8 = (lane >> 4) * 8, lq = lane >> 4;
    const u16* ab  = Wcb + (size_t)(rt * 128) * 1024 + h * 64;
    const u16* bm  = Bmb + (size_t)h * 4096;
    f32x4 acc[2][4] = {};
#pragma unroll
    for(int i = 0; i < 2; i++){
      int mf = wid * 2 + i;
#pragma unroll
      for(int ks = 0; ks < 2; ks++){
        bf16x8 a = *(const bf16x8*)(ab + (size_t)(mf * 16 + lr) * 1024 + ks * 32 + lk8);
#pragma unroll
        for(int nf = 0; nf < 4; nf++){
          bf16x8 bfr = *(const bf16x8*)(bm + (nf * 16 + lr) * 64 + ks * 32 + lk8);
          acc[i][nf] = __builtin_amdgcn_mfma_f32_16x16x32_bf16(a, bfr, acc[i][nf], 0, 0, 0);
        }
      }
    }
#pragma unroll
    for(int i = 0; i < 2; i++)
#pragma unroll
      for(int nf = 0; nf < 4; nf++)
#pragma unroll
        for(int r = 0; r < 4; r++){
          int row = rt * 128 + (wid * 2 + i) * 16 + lq * 4 + r;
          int col = h * 64 + nf * 16 + lr;
          Wcpb[(size_t)row * 1024 + col] = f2bf(acc[i][nf][r]);
        }
    return;
  }
  int sel = blockIdx.y >> 3, byl = blockIdx.y & 7;
  const u16* W = sel == 0 ? Wq : sel == 1 ? Wk : Wv;
  u16* C = sel == 0 ? Q : sel == 1 ? Ko : V;
  gemm128_p2<u16>(Xb, W, C, blockIdx.x, byl, 1024, 1024);
}

__global__ __launch_bounds__(256) void out_gemm(
    const u16* __restrict__ Yb, const u16* __restrict__ Wcpb, float* __restrict__ out)
{
  gemm128_p2<float>(Yb, Wcpb, out, blockIdx.x, blockIdx.y, 1024, 1024);
}

// ---------------- state_chunk: fused K/V transpose + per-chunk state ----------------
__global__ __launch_bounds__(256) void state_chunk(
    const u16* __restrict__ Kb, const u16* __restrict__ Vb,
    u16* __restrict__ VT, float* __restrict__ Sc)
{
  int bh = blockIdx.x, c = blockIdx.y;
  int b = bh >> 4, h = bh & 15;
  int tid = threadIdx.x;
  __shared__ u16 Kt[128][72];
  __shared__ u16 Vt[128][72];
  int rr = tid >> 3;            // 0..31
  int cc = (tid & 7) * 8;       // 0..56
  const u16* kg = Kb + (size_t)(b * 2048 + c * 128) * 1024 + h * 64;
  const u16* vg = Vb + (size_t)(b * 2048 + c * 128) * 1024 + h * 64;
#pragma unroll
  for(int p = 0; p < 4; p++){
    int row = rr + p * 32;
    *(int4*)&Kt[row][cc] = *(const int4*)(kg + (size_t)row * 1024 + cc);
    *(int4*)&Vt[row][cc] = *(const int4*)(vg + (size_t)row * 1024 + cc);
  }
  __syncthreads();
  {
    int d = tid >> 2, tseg = (tid & 3) * 32;
    u16* vto = VT + (size_t)bh * 64 * 2048 + (size_t)d * 2048 + c * 128 + tseg;
#pragma unroll
    for(int j = 0; j < 32; j += 8){
      u16 tmp[8] __attribute__((aligned(16)));
#pragma unroll
      for(int q = 0; q < 8; q++) tmp[q] = Vt[tseg + j + q][d];
      *(int4*)(vto + j) = *(const int4*)tmp;
    }
  }
  int wid = tid >> 6, lane = tid & 63;
  int wr = wid >> 1, wc = wid & 1;
  int lr = lane & 15, lk8 = (lane >> 4) * 8, lq = lane >> 4;
  f32x4 acc[2][2] = {};
#pragma unroll
  for(int ks = 0; ks < 4; ks++){
    bf16x8 a[2], bb[2];
#pragma unroll
    for(int i = 0; i < 2; i++){
      u16 tmp[8] __attribute__((aligned(16)));
      int e = wr * 32 + i * 16 + lr;
#pragma unroll
      for(int q = 0; q < 8; q++) tmp[q] = Vt[ks * 32 + lk8 + q][e];
      a[i] = *(const bf16x8*)tmp;
    }
#pragma unroll
    for(int j = 0; j < 2; j++){
      u16 tmp[8] __attribute__((aligned(16)));
      int dk = wc * 32 + j * 16 + lr;
#pragma unroll
      for(int q = 0; q < 8; q++) tmp[q] = Kt[ks * 32 + lk8 + q][dk];
      bb[j] = *(const bf16x8*)tmp;
    }
#pragma unroll
    for(int i = 0; i < 2; i++)
#pragma unroll
      for(int j = 0; j < 2; j++)
        acc[i][j] = __builtin_amdgcn_mfma_f32_16x16x32_bf16(a[i], bb[j], acc[i][j], 0, 0, 0);
  }
  float* out = Sc + ((size_t)bh * 16 + c) * 4096;
#pragma unroll
  for(int i = 0; i < 2; i++)
#pragma unroll
    for(int j = 0; j < 2; j++)
#pragma unroll
      for(int r = 0; r < 4; r++){
        int e = wr * 32 + i * 16 + lq * 4 + r, dk = wc * 32 + j * 16 + lr;
        out[e * 64 + dk] = acc[i][j][r];
      }
}

// ---------------- prefix: exclusive chunk prefix, float4-vectorized ----------------
__global__ __launch_bounds__(256) void prefix_state(const float* __restrict__ Sc, u16* __restrict__ Scb)
{
  int bh = blockIdx.x >> 2, part = blockIdx.x & 3;
  int e4 = part * 256 + threadIdx.x;   // float4 index 0..1023
  const float4* s = (const float4*)(Sc + (size_t)bh * 65536) + e4;
  u16* d = Scb + (size_t)bh * 65536 + e4 * 4;
  float4 run = {0.f, 0.f, 0.f, 0.f};
  for(int c = 0; c < 16; c++){
    float4 v = s[(size_t)c * 1024];
    u64 pk = (u64)f2bf(run.x) | ((u64)f2bf(run.y) << 16) | ((u64)f2bf(run.z) << 32) | ((u64)f2bf(run.w) << 48);
    *(u64*)(d + (size_t)c * 4096) = pk;
    run.x += v.x; run.y += v.y; run.z += v.z; run.w += v.w;
  }
}

// ---------------- chunk_attn: Y = Q@stateT^T + tril(Q@K^T)@V, barrier-free ----------------
__global__ __launch_bounds__(256) void chunk_attn(
    const u16* __restrict__ Q, const u16* __restrict__ Kmat,
    const u16* __restrict__ VT, const u16* __restrict__ Scb, u16* __restrict__ Y)
{
  int bh = blockIdx.x, c = blockIdx.y;
  int b = bh >> 4, h = bh & 15;
  int t = threadIdx.x, wid = t >> 6, lane = t & 63;
  int lr = lane & 15, lk8 = (lane >> 4) * 8, lq = lane >> 4;
  __shared__ u16 S[128 * 128];  // XOR-swizzled; each wave touches only its own rows
  const u16* qg = Q    + (size_t)(b * 2048 + c * 128) * 1024 + h * 64;
  const u16* kg = Kmat + (size_t)(b * 2048 + c * 128) * 1024 + h * 64;
  const u16* scb = Scb + ((size_t)bh * 16 + c) * 4096;
  const u16* vt  = VT + (size_t)bh * 64 * 2048 + (size_t)c * 128;
  u16* yg = Y + (size_t)(b * 2048 + c * 128) * 1024 + h * 64;
#pragma unroll
  for(int mi = 0; mi < 2; mi++){
    int mf = wid + mi * 4;
    int Rm = mf * 16;
    if((mf & 1) == 0){
      int zr = Rm + (lane >> 2), zc = Rm + 16 + (lane & 3) * 4;
      int zoff = ((zr * 128 + zc) * 2) ^ ((zr & 7) << 4);
      *(u64*)((char*)S + zoff) = 0ULL;
    }
    bf16x8 a[2];
#pragma unroll
    for(int ks = 0; ks < 2; ks++) a[ks] = *(const bf16x8*)(qg + (size_t)(Rm + lr) * 1024 + ks * 32 + lk8);
    for(int nf = 0; nf <= mf; nf++){
      f32x4 acc = {};
#pragma unroll
      for(int ks = 0; ks < 2; ks++){
        bf16x8 bb = *(const bf16x8*)(kg + (size_t)(nf * 16 + lr) * 1024 + ks * 32 + lk8);
        acc = __builtin_amdgcn_mfma_f32_16x16x32_bf16(a[ks], bb, acc, 0, 0, 0);
      }
#pragma unroll
      for(int r = 0; r < 4; r++){
        int row = lq * 4 + r, col = lr;
        float v = acc[r];
        if(nf == mf && col > row) v = 0.f;
        int grow = Rm + row, gcol = nf * 16 + col;
        int off = ((grow * 128 + gcol) * 2) ^ ((grow & 7) << 4);
        *(u16*)((char*)S + off) = f2bf(v);
      }
    }
    f32x4 acc2[4] = {};
#pragma unroll
    for(int nf = 0; nf < 4; nf++){
#pragma unroll
      for(int ks = 0; ks < 2; ks++){
        bf16x8 bb = *(const bf16x8*)(scb + (nf * 16 + lr) * 64 + ks * 32 + lk8);
        acc2[nf] = __builtin_amdgcn_mfma_f32_16x16x32_bf16(a[ks], bb, acc2[nf], 0, 0, 0);
      }
    }
    int ksmax = mf >> 1;
    for(int ks = 0; ks <= ksmax; ks++){
      int row = Rm + lr;
      int off = ((row * 128 + ks * 32 + lk8) * 2) ^ ((row & 7) << 4);
      bf16x8 af = *(const bf16x8*)((char*)S + off);
#pragma unroll
      for(int nf = 0; nf < 4; nf++){
        bf16x8 bb = *(const bf16x8*)(vt + (size_t)(nf * 16 + lr) * 2048 + ks * 32 + lk8);
        acc2[nf] = __builtin_amdgcn_mfma_f32_16x16x32_bf16(af, bb, acc2[nf], 0, 0, 0);
      }
    }
#pragma unroll
    for(int nf = 0; nf < 4; nf++)
#pragma unroll
      for(int r = 0; r < 4; r++){
        int grow = Rm + lq * 4 + r, gcol = nf * 16 + lr;
        yg[(size_t)grow * 1024 + gcol] = f2bf(acc2[nf][r]);
      }
  }
}

// ---------------- launch ----------------
extern "C" void kernel_launch(void* const* d_in, const int* in_sizes, int n_in,
                              void* d_out, int out_size, void* d_ws, size_t ws_size,
                              hipStream_t stream)
{
  const float* X    = (const float*)d_in[0];
  const float* Wq   = (const float*)d_in[1];
  const float* Wk   = (const float*)d_in[2];
  const float* Wv   = (const float*)d_in[3];
  const float* Wc   = (const float*)d_in[4];
  const float* Ltri = (const float*)d_in[5];
  float* out = (float*)d_out;

  char* ws = (char*)d_ws;
  size_t off = 0;
  auto carve = [&](size_t bytes) -> char* {
    char* p = ws + off;
    off += (bytes + 255) & ~(size_t)255;
    return p;
  };
  u16* Xb   = (u16*)carve((size_t)4194304 * 2);
  u16* Wqb  = (u16*)carve((size_t)1048576 * 2);
  u16* Wkb  = (u16*)carve((size_t)1048576 * 2);
  u16* Wvb  = (u16*)carve((size_t)1048576 * 2);
  u16* Wcb  = (u16*)carve((size_t)1048576 * 2);
  u16* Wcpb = (u16*)carve((size_t)1048576 * 2);
  u16* Bmb  = (u16*)carve((size_t)65536 * 2);
  u16* Qb   = (u16*)carve((size_t)4194304 * 2);
  u16* Kb   = (u16*)carve((size_t)4194304 * 2);
  u16* Vb   = (u16*)carve((size_t)4194304 * 2);
  u16* VT   = (u16*)carve((size_t)4194304 * 2);
  float* Sc = (float*)carve((size_t)2097152 * 4);
  u16* Scb  = (u16*)carve((size_t)2097152 * 2);
  u16* Yb   = (u16*)carve((size_t)4194304 * 2);
  (void)in_sizes; (void)n_in; (void)out_size; (void)ws_size;

  prep_kernel<<<2064, 256, 0, stream>>>(X, Xb, Wq, Wqb, Wk, Wkb, Wv, Wvb, Wc, Wcb, Ltri, Bmb);
  qkv_gemm<<<dim3(32, 28), 256, 0, stream>>>(Xb, Wqb, Wkb, Wvb, Qb, Kb, Vb, Wcb, Bmb, Wcpb);
  state_chunk<<<dim3(32, 16), 256, 0, stream>>>(Kb, Vb, VT, Sc);
  prefix_state<<<128, 256, 0, stream>>>(Sc, Scb);
  chunk_attn<<<dim3(32, 16), 256, 0, stream>>>(Qb, Kb, VT, Scb, Yb);
  out_gemm<<<dim3(32, 8), 256, 0, stream>>>(Yb, Wcpb, out);
}

// Round 5
// 105.998 us; speedup vs baseline: 1.4575x; 1.0072x over previous
//
#include <hip/hip_runtime.h>

// LinearAttentionSVAR: B=2, L=2048, D=1024, H=16, d=64.
// Round 5: kill the 8-way LDS bank conflict in the GEMM fragment reads.
//  - gemm128_p2: BK=64 tiles (128B rows), XOR chunk-swizzle (chunk ^= row&7)
//    applied on BOTH sides: pre-swizzled global source for global_load_lds
//    (linear LDS dest) + swizzled ds_read addresses. 2 LDS bufs (64KB),
//    counted vmcnt(8), 2 barriers/tile, loads never drained mid-loop.
//  - prep / Wc' fold / state_chunk / prefix / chunk_attn unchanged.

#define DEV static __device__ __forceinline__

typedef unsigned short u16;
typedef unsigned long long u64;
typedef __attribute__((ext_vector_type(4))) float f32x4;
typedef __attribute__((ext_vector_type(8))) short bf16x8;

DEV u16 f2bf(float f){
  union { float f; unsigned u; } v; v.f = f;
  unsigned r = v.u + 0x7FFFu + ((v.u >> 16) & 1u);
  return (u16)(r >> 16);
}

DEV void store_val(float* p, float v){ *p = v; }
DEV void store_val(u16* p, float v){ *p = f2bf(v); }

DEV void gload16(const void* g, void* l){
  __builtin_amdgcn_global_load_lds((const __attribute__((address_space(1))) void*)g,
                                   (__attribute__((address_space(3))) void*)l, 16, 0, 0);
}

// ---------------- 1. prep: bf16 converts + per-head Bm ----------------
__global__ __launch_bounds__(256) void prep_kernel(
    const float* __restrict__ X, u16* __restrict__ Xb,
    const float* __restrict__ Wq, u16* __restrict__ Wqb,
    const float* __restrict__ Wk, u16* __restrict__ Wkb,
    const float* __restrict__ Wv, u16* __restrict__ Wvb,
    const float* __restrict__ Wc, u16* __restrict__ Wcb,
    const float* __restrict__ Ltri, u16* __restrict__ Bmb)
{
  const int bx = blockIdx.x, tid = threadIdx.x;
  if(bx < 16){
    __shared__ float Lm[64][65];
    int h = bx;
    const float* src = Ltri + (size_t)h * 4096;
    for(int i = tid; i < 4096; i += 256){
      int e = i >> 6, k = i & 63;
      Lm[e][k] = (k <= e) ? src[i] : 0.f;
    }
    __syncthreads();
    u16* out = Bmb + (size_t)h * 4096;
    for(int i = tid; i < 4096; i += 256){
      int e = i >> 6, dk = i & 63;
      float sum = 0.f;
      int kmax = e < dk ? e : dk;
      for(int k = 0; k <= kmax; k++) sum += Lm[e][k] * Lm[dk][k];
      out[i] = f2bf(sum);
    }
  } else {
    const int n0 = 4194304, n1 = 1048576, n2 = 1048576, n3 = 1048576, n4 = 1048576;
    int total = (n0 + n1 + n2 + n3 + n4) >> 2;
    for(int i = (bx - 16) * 256 + tid; i < total; i += 2048 * 256){
      int e = i << 2;
      const float* s; u16* d;
      if(e < n0){ s = X + e; d = Xb + e; }
      else if(e < n0 + n1){ s = Wq + (e - n0); d = Wqb + (e - n0); }
      else if(e < n0 + n1 + n2){ s = Wk + (e - n0 - n1); d = Wkb + (e - n0 - n1); }
      else if(e < n0 + n1 + n2 + n3){ s = Wv + (e - n0 - n1 - n2); d = Wvb + (e - n0 - n1 - n2); }
      else { s = Wc + (e - n0 - n1 - n2 - n3); d = Wcb + (e - n0 - n1 - n2 - n3); }
      float4 v = *(const float4*)s;
      u64 pk = (u64)f2bf(v.x) | ((u64)f2bf(v.y) << 16) | ((u64)f2bf(v.z) << 32) | ((u64)f2bf(v.w) << 48);
      *(u64*)d = pk;
    }
  }
}

// ---------------- GEMM tile body: BK=64, XOR-swizzled LDS, counted vmcnt ----------------
// LDS logical layout per buf: A[128][64] u16 at [0,8192), B at [8192,16384).
// Physical: element (row, chunk*8+w) lives at row*64 + ((chunk^(row&7))*8) + w.
// Stage writes linear (global_load_lds), so the SOURCE chunk is pre-permuted.
template<typename OutT>
DEV void gemm128_p2(const u16* __restrict__ A, const u16* __restrict__ W,
                    OutT* __restrict__ C, int bx, int by, int N, int K)
{
  __shared__ u16 L[2][16384];   // 64 KB total
  const int tid = threadIdx.x;
  const int wid = tid >> 6, lane = tid & 63;
  const int wr = wid >> 1, wc = wid & 1;
  const int lr = lane & 15, lq = lane >> 4, lk8 = lq * 8;
  const int srow = tid >> 3;      // 0..31 (plus p*32)
  const int schunk = tid & 7;
  const u16* Ag = A + (size_t)(bx * 128) * K;
  const u16* Wg = W + (size_t)(by * 128) * K;

  auto stagef = [&](int kt, int buf){
#pragma unroll
    for(int p = 0; p < 4; p++){
      int row = p * 32 + srow;
      int sc = ((schunk ^ (row & 7)) * 8);
      gload16(Ag + (size_t)row * K + kt * 64 + sc, &L[buf][p * 2048 + tid * 8]);
    }
#pragma unroll
    for(int p = 0; p < 4; p++){
      int row = p * 32 + srow;
      int sc = ((schunk ^ (row & 7)) * 8);
      gload16(Wg + (size_t)row * K + kt * 64 + sc, &L[buf][8192 + p * 2048 + tid * 8]);
    }
  };

  const int nt = K >> 6;
  f32x4 acc[4][4] = {};
  stagef(0, 0);
  for(int t = 0; t < nt; t++){
    if(t + 1 < nt){
      stagef(t + 1, (t + 1) & 1);
      asm volatile("s_waitcnt vmcnt(8)" ::: "memory");
    } else {
      asm volatile("s_waitcnt vmcnt(0)" ::: "memory");
    }
    __builtin_amdgcn_s_barrier();
    __builtin_amdgcn_sched_barrier(0);
    const u16* Lb = L[t & 1];
#pragma unroll
    for(int ks = 0; ks < 2; ks++){
      bf16x8 af[4], bfr[4];
#pragma unroll
      for(int i = 0; i < 4; i++){
        int row = wr * 64 + i * 16 + lr;
        af[i] = *(const bf16x8*)&Lb[row * 64 + (((ks * 4 + lq) ^ (row & 7)) * 8)];
      }
#pragma unroll
      for(int j = 0; j < 4; j++){
        int row = wc * 64 + j * 16 + lr;
        bfr[j] = *(const bf16x8*)&Lb[8192 + row * 64 + (((ks * 4 + lq) ^ (row & 7)) * 8)];
      }
#pragma unroll
      for(int i = 0; i < 4; i++)
#pragma unroll
        for(int j = 0; j < 4; j++)
          acc[i][j] = __builtin_amdgcn_mfma_f32_16x16x32_bf16(af[i], bfr[j], acc[i][j], 0, 0, 0);
    }
    __builtin_amdgcn_s_barrier();
  }
#pragma unroll
  for(int i = 0; i < 4; i++)
#pragma unroll
    for(int j = 0; j < 4; j++)
#pragma unroll
      for(int r = 0; r < 4; r++){
        int row = bx * 128 + wr * 64 + i * 16 + lq * 4 + r;
        int col = by * 128 + wc * 64 + j * 16 + lr;
        store_val(C + (size_t)row * N + col, acc[i][j][r]);
      }
}

// fused QKV projection + Wc' fold.
__global__ __launch_bounds__(256) void qkv_gemm(
    const u16* __restrict__ Xb,
    const u16* __restrict__ Wq, const u16* __restrict__ Wk, const u16* __restrict__ Wv,
    u16* __restrict__ Q, u16* __restrict__ Ko, u16* __restrict__ V,
    const u16* __restrict__ Wcb, const u16* __restrict__ Bmb, u16* __restrict__ Wcpb)
{
  if(blockIdx.y >= 24){
    // Wc'_h[128 rows x 64 cols] = Wc_h @ Bm_h^T (Bm symmetric), K = 64.
    int rt = blockIdx.x & 7, h = (blockIdx.x >> 3) + ((blockIdx.y - 24) << 2);
    int wid = threadIdx.x >> 6, lane = threadIdx.x & 63;
    int lr = lane & 15, lk8 = (lane >> 4) * 8, lq = lane >> 4;
    const u16* ab  = Wcb + (size_t)(rt * 128) * 1024 + h * 64;
    const u16* bm  = Bmb + (size_t)h * 4096;
    f32x4 acc[2][4] = {};
#pragma unroll
    for(int i = 0; i < 2; i++){
      int mf = wid * 2 + i;
#pragma unroll
      for(int ks = 0; ks < 2; ks++){
        bf16x8 a = *(const bf16x8*)(ab + (size_t)(mf * 16 + lr) * 1024 + ks * 32 + lk8);
#pragma unroll
        for(int nf = 0; nf < 4; nf++){
          bf16x8 bfr = *(const bf16x8*)(bm + (nf * 16 + lr) * 64 + ks * 32 + lk8);
          acc[i][nf] = __builtin_amdgcn_mfma_f32_16x16x32_bf16(a, bfr, acc[i][nf], 0, 0, 0);
        }
      }
    }
#pragma unroll
    for(int i = 0; i < 2; i++)
#pragma unroll
      for(int nf = 0; nf < 4; nf++)
#pragma unroll
        for(int r = 0; r < 4; r++){
          int row = rt * 128 + (wid * 2 + i) * 16 + lq * 4 + r;
          int col = h * 64 + nf * 16 + lr;
          Wcpb[(size_t)row * 1024 + col] = f2bf(acc[i][nf][r]);
        }
    return;
  }
  int sel = blockIdx.y >> 3, byl = blockIdx.y & 7;
  const u16* W = sel == 0 ? Wq : sel == 1 ? Wk : Wv;
  u16* C = sel == 0 ? Q : sel == 1 ? Ko : V;
  gemm128_p2<u16>(Xb, W, C, blockIdx.x, byl, 1024, 1024);
}

__global__ __launch_bounds__(256) void out_gemm(
    const u16* __restrict__ Yb, const u16* __restrict__ Wcpb, float* __restrict__ out)
{
  gemm128_p2<float>(Yb, Wcpb, out, blockIdx.x, blockIdx.y, 1024, 1024);
}

// ---------------- state_chunk: fused K/V transpose + per-chunk state ----------------
__global__ __launch_bounds__(256) void state_chunk(
    const u16* __restrict__ Kb, const u16* __restrict__ Vb,
    u16* __restrict__ VT, float* __restrict__ Sc)
{
  int bh = blockIdx.x, c = blockIdx.y;
  int b = bh >> 4, h = bh & 15;
  int tid = threadIdx.x;
  __shared__ u16 Kt[128][72];
  __shared__ u16 Vt[128][72];
  int rr = tid >> 3;            // 0..31
  int cc = (tid & 7) * 8;       // 0..56
  const u16* kg = Kb + (size_t)(b * 2048 + c * 128) * 1024 + h * 64;
  const u16* vg = Vb + (size_t)(b * 2048 + c * 128) * 1024 + h * 64;
#pragma unroll
  for(int p = 0; p < 4; p++){
    int row = rr + p * 32;
    *(int4*)&Kt[row][cc] = *(const int4*)(kg + (size_t)row * 1024 + cc);
    *(int4*)&Vt[row][cc] = *(const int4*)(vg + (size_t)row * 1024 + cc);
  }
  __syncthreads();
  {
    int d = tid >> 2, tseg = (tid & 3) * 32;
    u16* vto = VT + (size_t)bh * 64 * 2048 + (size_t)d * 2048 + c * 128 + tseg;
#pragma unroll
    for(int j = 0; j < 32; j += 8){
      u16 tmp[8] __attribute__((aligned(16)));
#pragma unroll
      for(int q = 0; q < 8; q++) tmp[q] = Vt[tseg + j + q][d];
      *(int4*)(vto + j) = *(const int4*)tmp;
    }
  }
  int wid = tid >> 6, lane = tid & 63;
  int wr = wid >> 1, wc = wid & 1;
  int lr = lane & 15, lk8 = (lane >> 4) * 8, lq = lane >> 4;
  f32x4 acc[2][2] = {};
#pragma unroll
  for(int ks = 0; ks < 4; ks++){
    bf16x8 a[2], bb[2];
#pragma unroll
    for(int i = 0; i < 2; i++){
      u16 tmp[8] __attribute__((aligned(16)));
      int e = wr * 32 + i * 16 + lr;
#pragma unroll
      for(int q = 0; q < 8; q++) tmp[q] = Vt[ks * 32 + lk8 + q][e];
      a[i] = *(const bf16x8*)tmp;
    }
#pragma unroll
    for(int j = 0; j < 2; j++){
      u16 tmp[8] __attribute__((aligned(16)));
      int dk = wc * 32 + j * 16 + lr;
#pragma unroll
      for(int q = 0; q < 8; q++) tmp[q] = Kt[ks * 32 + lk8 + q][dk];
      bb[j] = *(const bf16x8*)tmp;
    }
#pragma unroll
    for(int i = 0; i < 2; i++)
#pragma unroll
      for(int j = 0; j < 2; j++)
        acc[i][j] = __builtin_amdgcn_mfma_f32_16x16x32_bf16(a[i], bb[j], acc[i][j], 0, 0, 0);
  }
  float* out = Sc + ((size_t)bh * 16 + c) * 4096;
#pragma unroll
  for(int i = 0; i < 2; i++)
#pragma unroll
    for(int j = 0; j < 2; j++)
#pragma unroll
      for(int r = 0; r < 4; r++){
        int e = wr * 32 + i * 16 + lq * 4 + r, dk = wc * 32 + j * 16 + lr;
        out[e * 64 + dk] = acc[i][j][r];
      }
}

// ---------------- prefix: exclusive chunk prefix, float4-vectorized ----------------
__global__ __launch_bounds__(256) void prefix_state(const float* __restrict__ Sc, u16* __restrict__ Scb)
{
  int bh = blockIdx.x >> 2, part = blockIdx.x & 3;
  int e4 = part * 256 + threadIdx.x;   // float4 index 0..1023
  const float4* s = (const float4*)(Sc + (size_t)bh * 65536) + e4;
  u16* d = Scb + (size_t)bh * 65536 + e4 * 4;
  float4 run = {0.f, 0.f, 0.f, 0.f};
  for(int c = 0; c < 16; c++){
    float4 v = s[(size_t)c * 1024];
    u64 pk = (u64)f2bf(run.x) | ((u64)f2bf(run.y) << 16) | ((u64)f2bf(run.z) << 32) | ((u64)f2bf(run.w) << 48);
    *(u64*)(d + (size_t)c * 4096) = pk;
    run.x += v.x; run.y += v.y; run.z += v.z; run.w += v.w;
  }
}

// ---------------- chunk_attn: Y = Q@stateT^T + tril(Q@K^T)@V, barrier-free ----------------
__global__ __launch_bounds__(256) void chunk_attn(
    const u16* __restrict__ Q, const u16* __restrict__ Kmat,
    const u16* __restrict__ VT, const u16* __restrict__ Scb, u16* __restrict__ Y)
{
  int bh = blockIdx.x, c = blockIdx.y;
  int b = bh >> 4, h = bh & 15;
  int t = threadIdx.x, wid = t >> 6, lane = t & 63;
  int lr = lane & 15, lk8 = (lane >> 4) * 8, lq = lane >> 4;
  __shared__ u16 S[128 * 128];  // XOR-swizzled; each wave touches only its own rows
  const u16* qg = Q    + (size_t)(b * 2048 + c * 128) * 1024 + h * 64;
  const u16* kg = Kmat + (size_t)(b * 2048 + c * 128) * 1024 + h * 64;
  const u16* scb = Scb + ((size_t)bh * 16 + c) * 4096;
  const u16* vt  = VT + (size_t)bh * 64 * 2048 + (size_t)c * 128;
  u16* yg = Y + (size_t)(b * 2048 + c * 128) * 1024 + h * 64;
#pragma unroll
  for(int mi = 0; mi < 2; mi++){
    int mf = wid + mi * 4;
    int Rm = mf * 16;
    if((mf & 1) == 0){
      int zr = Rm + (lane >> 2), zc = Rm + 16 + (lane & 3) * 4;
      int zoff = ((zr * 128 + zc) * 2) ^ ((zr & 7) << 4);
      *(u64*)((char*)S + zoff) = 0ULL;
    }
    bf16x8 a[2];
#pragma unroll
    for(int ks = 0; ks < 2; ks++) a[ks] = *(const bf16x8*)(qg + (size_t)(Rm + lr) * 1024 + ks * 32 + lk8);
    for(int nf = 0; nf <= mf; nf++){
      f32x4 acc = {};
#pragma unroll
      for(int ks = 0; ks < 2; ks++){
        bf16x8 bb = *(const bf16x8*)(kg + (size_t)(nf * 16 + lr) * 1024 + ks * 32 + lk8);
        acc = __builtin_amdgcn_mfma_f32_16x16x32_bf16(a[ks], bb, acc, 0, 0, 0);
      }
#pragma unroll
      for(int r = 0; r < 4; r++){
        int row = lq * 4 + r, col = lr;
        float v = acc[r];
        if(nf == mf && col > row) v = 0.f;
        int grow = Rm + row, gcol = nf * 16 + col;
        int off = ((grow * 128 + gcol) * 2) ^ ((grow & 7) << 4);
        *(u16*)((char*)S + off) = f2bf(v);
      }
    }
    f32x4 acc2[4] = {};
#pragma unroll
    for(int nf = 0; nf < 4; nf++){
#pragma unroll
      for(int ks = 0; ks < 2; ks++){
        bf16x8 bb = *(const bf16x8*)(scb + (nf * 16 + lr) * 64 + ks * 32 + lk8);
        acc2[nf] = __builtin_amdgcn_mfma_f32_16x16x32_bf16(a[ks], bb, acc2[nf], 0, 0, 0);
      }
    }
    int ksmax = mf >> 1;
    for(int ks = 0; ks <= ksmax; ks++){
      int row = Rm + lr;
      int off = ((row * 128 + ks * 32 + lk8) * 2) ^ ((row & 7) << 4);
      bf16x8 af = *(const bf16x8*)((char*)S + off);
#pragma unroll
      for(int nf = 0; nf < 4; nf++){
        bf16x8 bb = *(const bf16x8*)(vt + (size_t)(nf * 16 + lr) * 2048 + ks * 32 + lk8);
        acc2[nf] = __builtin_amdgcn_mfma_f32_16x16x32_bf16(af, bb, acc2[nf], 0, 0, 0);
      }
    }
#pragma unroll
    for(int nf = 0; nf < 4; nf++)
#pragma unroll
      for(int r = 0; r < 4; r++){
        int grow = Rm + lq * 4 + r, gcol = nf * 16 + lr;
        yg[(size_t)grow * 1024 + gcol] = f2bf(acc2[nf][r]);
      }
  }
}

// ---------------- launch ----------------
extern "C" void kernel_launch(void* const* d_in, const int* in_sizes, int n_in,
                              void* d_out, int out_size, void* d_ws, size_t ws_size,
                              hipStream_t stream)
{
  const float* X    = (const float*)d_in[0];
  const float* Wq   = (const float*)d_in[1];
  const float* Wk   = (const float*)d_in[2];
  const float* Wv   = (const float*)d_in[3];
  const float* Wc   = (const float*)d_in[4];
  const float* Ltri = (const float*)d_in[5];
  float* out = (float*)d_out;

  char* ws = (char*)d_ws;
  size_t off = 0;
  auto carve = [&](size_t bytes) -> char* {
    char* p = ws + off;
    off += (bytes + 255) & ~(size_t)255;
    return p;
  };
  u16* Xb   = (u16*)carve((size_t)4194304 * 2);
  u16* Wqb  = (u16*)carve((size_t)1048576 * 2);
  u16* Wkb  = (u16*)carve((size_t)1048576 * 2);
  u16* Wvb  = (u16*)carve((size_t)1048576 * 2);
  u16* Wcb  = (u16*)carve((size_t)1048576 * 2);
  u16* Wcpb = (u16*)carve((size_t)1048576 * 2);
  u16* Bmb  = (u16*)carve((size_t)65536 * 2);
  u16* Qb   = (u16*)carve((size_t)4194304 * 2);
  u16* Kb   = (u16*)carve((size_t)4194304 * 2);
  u16* Vb   = (u16*)carve((size_t)4194304 * 2);
  u16* VT   = (u16*)carve((size_t)4194304 * 2);
  float* Sc = (float*)carve((size_t)2097152 * 4);
  u16* Scb  = (u16*)carve((size_t)2097152 * 2);
  u16* Yb   = (u16*)carve((size_t)4194304 * 2);
  (void)in_sizes; (void)n_in; (void)out_size; (void)ws_size;

  prep_kernel<<<2064, 256, 0, stream>>>(X, Xb, Wq, Wqb, Wk, Wkb, Wv, Wvb, Wc, Wcb, Ltri, Bmb);
  qkv_gemm<<<dim3(32, 28), 256, 0, stream>>>(Xb, Wqb, Wkb, Wvb, Qb, Kb, Vb, Wcb, Bmb, Wcpb);
  state_chunk<<<dim3(32, 16), 256, 0, stream>>>(Kb, Vb, VT, Sc);
  prefix_state<<<128, 256, 0, stream>>>(Sc, Scb);
  chunk_attn<<<dim3(32, 16), 256, 0, stream>>>(Qb, Kb, VT, Scb, Yb);
  out_gemm<<<dim3(32, 8), 256, 0, stream>>>(Yb, Wcpb, out);
}

// Round 6
// 105.069 us; speedup vs baseline: 1.4704x; 1.0088x over previous
//
#include <hip/hip_runtime.h>

// LinearAttentionSVAR: B=2, L=2048, D=1024, H=16, d=64.
// Round 6: occupancy AND conflict-free GEMM.
//  - gemm128_p2: BK=32, 3 LDS buffers (48KB -> 3 blocks/CU), depth-2 prefetch,
//    counted vmcnt(4), one barrier/tile (round-4 skeleton), PLUS row-pair-fused
//    XOR swizzle: physical line p=row>>1 is 128B (8x16B chunks),
//    cphys = (kc | ((row&1)<<2)) ^ (p&7). Fragment reads: 16 lanes hit all 8
//    chunks exactly twice -> 2-way = free. Staged via pre-swizzled global
//    source (linear global_load_lds dest), read with the same XOR.
//  - prep / Wc' fold / state_chunk / prefix / chunk_attn unchanged.

#define DEV static __device__ __forceinline__

typedef unsigned short u16;
typedef unsigned long long u64;
typedef __attribute__((ext_vector_type(4))) float f32x4;
typedef __attribute__((ext_vector_type(8))) short bf16x8;

DEV u16 f2bf(float f){
  union { float f; unsigned u; } v; v.f = f;
  unsigned r = v.u + 0x7FFFu + ((v.u >> 16) & 1u);
  return (u16)(r >> 16);
}

DEV void store_val(float* p, float v){ *p = v; }
DEV void store_val(u16* p, float v){ *p = f2bf(v); }

DEV void gload16(const void* g, void* l){
  __builtin_amdgcn_global_load_lds((const __attribute__((address_space(1))) void*)g,
                                   (__attribute__((address_space(3))) void*)l, 16, 0, 0);
}

// ---------------- 1. prep: bf16 converts + per-head Bm ----------------
__global__ __launch_bounds__(256) void prep_kernel(
    const float* __restrict__ X, u16* __restrict__ Xb,
    const float* __restrict__ Wq, u16* __restrict__ Wqb,
    const float* __restrict__ Wk, u16* __restrict__ Wkb,
    const float* __restrict__ Wv, u16* __restrict__ Wvb,
    const float* __restrict__ Wc, u16* __restrict__ Wcb,
    const float* __restrict__ Ltri, u16* __restrict__ Bmb)
{
  const int bx = blockIdx.x, tid = threadIdx.x;
  if(bx < 16){
    __shared__ float Lm[64][65];
    int h = bx;
    const float* src = Ltri + (size_t)h * 4096;
    for(int i = tid; i < 4096; i += 256){
      int e = i >> 6, k = i & 63;
      Lm[e][k] = (k <= e) ? src[i] : 0.f;
    }
    __syncthreads();
    u16* out = Bmb + (size_t)h * 4096;
    for(int i = tid; i < 4096; i += 256){
      int e = i >> 6, dk = i & 63;
      float sum = 0.f;
      int kmax = e < dk ? e : dk;
      for(int k = 0; k <= kmax; k++) sum += Lm[e][k] * Lm[dk][k];
      out[i] = f2bf(sum);
    }
  } else {
    const int n0 = 4194304, n1 = 1048576, n2 = 1048576, n3 = 1048576, n4 = 1048576;
    int total = (n0 + n1 + n2 + n3 + n4) >> 2;
    for(int i = (bx - 16) * 256 + tid; i < total; i += 2048 * 256){
      int e = i << 2;
      const float* s; u16* d;
      if(e < n0){ s = X + e; d = Xb + e; }
      else if(e < n0 + n1){ s = Wq + (e - n0); d = Wqb + (e - n0); }
      else if(e < n0 + n1 + n2){ s = Wk + (e - n0 - n1); d = Wkb + (e - n0 - n1); }
      else if(e < n0 + n1 + n2 + n3){ s = Wv + (e - n0 - n1 - n2); d = Wvb + (e - n0 - n1 - n2); }
      else { s = Wc + (e - n0 - n1 - n2 - n3); d = Wcb + (e - n0 - n1 - n2 - n3); }
      float4 v = *(const float4*)s;
      u64 pk = (u64)f2bf(v.x) | ((u64)f2bf(v.y) << 16) | ((u64)f2bf(v.z) << 32) | ((u64)f2bf(v.w) << 48);
      *(u64*)d = pk;
    }
  }
}

// ---------------- GEMM tile body: BK=32, row-pair-fused swizzle, depth-2 ----------------
// Per buf: A logical [128][32] in [0,4096) elems, B in [4096,8192).
// Physical elem addr of (row,k): (row>>1)*64 + cphys*8 + (k&7),
//   cphys = ((k>>3) | ((row&1)<<2)) ^ ((row>>1)&7).
// Staging writes linear (tid*8); the global SOURCE is pre-permuted to match.
template<typename OutT>
DEV void gemm128_p2(const u16* __restrict__ A, const u16* __restrict__ W,
                    OutT* __restrict__ C, int bx, int by, int N, int K)
{
  __shared__ u16 L[3][8192];   // 48 KB total -> 3 blocks/CU
  const int tid = threadIdx.x;
  const int wid = tid >> 6, lane = tid & 63;
  const int wr = wid >> 1, wc = wid & 1;
  const int lr = lane & 15, lq = lane >> 4;
  const u16* Ag = A + (size_t)(bx * 128) * K;
  const u16* Wg = W + (size_t)(by * 128) * K;

  // pre-swizzled source coords for this thread's 2 A-loads / 2 B-loads
  const int p0 = tid >> 3, p1 = 32 + (tid >> 3);
  const int cl0 = (tid & 7) ^ (p0 & 7);
  const int cl1 = (tid & 7) ^ (p1 & 7);
  const int srow0 = 2 * p0 + (cl0 >> 2), skc0 = (cl0 & 3) * 8;
  const int srow1 = 2 * p1 + (cl1 >> 2), skc1 = (cl1 & 3) * 8;

  auto stagef = [&](int kt, int buf){
    gload16(Ag + (size_t)srow0 * K + kt * 32 + skc0, &L[buf][tid * 8]);
    gload16(Ag + (size_t)srow1 * K + kt * 32 + skc1, &L[buf][2048 + tid * 8]);
    gload16(Wg + (size_t)srow0 * K + kt * 32 + skc0, &L[buf][4096 + tid * 8]);
    gload16(Wg + (size_t)srow1 * K + kt * 32 + skc1, &L[buf][6144 + tid * 8]);
  };

  const int nt = K >> 5;
  f32x4 acc[4][4] = {};
  stagef(0, 0);
  stagef(1, 1);
  int cur = 0;
  for(int t = 0; t < nt; t++){
    if(t < nt - 1) asm volatile("s_waitcnt vmcnt(4)" ::: "memory");
    else           asm volatile("s_waitcnt vmcnt(0)" ::: "memory");
    __builtin_amdgcn_s_barrier();
    __builtin_amdgcn_sched_barrier(0);
    if(t + 2 < nt){
      int n2 = cur >= 1 ? cur - 1 : cur + 2;   // (t+2)%3
      stagef(t + 2, n2);
    }
    const u16* Lb = L[cur];
    bf16x8 af[4], bfr[4];
#pragma unroll
    for(int i = 0; i < 4; i++){
      int row = wr * 64 + i * 16 + lr;
      int rh = row >> 1;
      int cph = (lq | ((row & 1) << 2)) ^ (rh & 7);
      af[i] = *(const bf16x8*)&Lb[rh * 64 + cph * 8];
    }
#pragma unroll
    for(int j = 0; j < 4; j++){
      int row = wc * 64 + j * 16 + lr;
      int rh = row >> 1;
      int cph = (lq | ((row & 1) << 2)) ^ (rh & 7);
      bfr[j] = *(const bf16x8*)&Lb[4096 + rh * 64 + cph * 8];
    }
#pragma unroll
    for(int i = 0; i < 4; i++)
#pragma unroll
      for(int j = 0; j < 4; j++)
        acc[i][j] = __builtin_amdgcn_mfma_f32_16x16x32_bf16(af[i], bfr[j], acc[i][j], 0, 0, 0);
    cur = cur == 2 ? 0 : cur + 1;
  }
#pragma unroll
  for(int i = 0; i < 4; i++)
#pragma unroll
    for(int j = 0; j < 4; j++)
#pragma unroll
      for(int r = 0; r < 4; r++){
        int row = bx * 128 + wr * 64 + i * 16 + (lane >> 4) * 4 + r;
        int col = by * 128 + wc * 64 + j * 16 + lr;
        store_val(C + (size_t)row * N + col, acc[i][j][r]);
      }
}

// fused QKV projection + Wc' fold.
__global__ __launch_bounds__(256) void qkv_gemm(
    const u16* __restrict__ Xb,
    const u16* __restrict__ Wq, const u16* __restrict__ Wk, const u16* __restrict__ Wv,
    u16* __restrict__ Q, u16* __restrict__ Ko, u16* __restrict__ V,
    const u16* __restrict__ Wcb, const u16* __restrict__ Bmb, u16* __restrict__ Wcpb)
{
  if(blockIdx.y >= 24){
    // Wc'_h[128 rows x 64 cols] = Wc_h @ Bm_h^T (Bm symmetric), K = 64.
    int rt = blockIdx.x & 7, h = (blockIdx.x >> 3) + ((blockIdx.y - 24) << 2);
    int wid = threadIdx.x >> 6, lane = threadIdx.x & 63;
    int lr = lane & 15, lk8 = (lane >> 4) * 8, lq = lane >> 4;
    const u16* ab  = Wcb + (size_t)(rt * 128) * 1024 + h * 64;
    const u16* bm  = Bmb + (size_t)h * 4096;
    f32x4 acc[2][4] = {};
#pragma unroll
    for(int i = 0; i < 2; i++){
      int mf = wid * 2 + i;
#pragma unroll
      for(int ks = 0; ks < 2; ks++){
        bf16x8 a = *(const bf16x8*)(ab + (size_t)(mf * 16 + lr) * 1024 + ks * 32 + lk8);
#pragma unroll
        for(int nf = 0; nf < 4; nf++){
          bf16x8 bfr = *(const bf16x8*)(bm + (nf * 16 + lr) * 64 + ks * 32 + lk8);
          acc[i][nf] = __builtin_amdgcn_mfma_f32_16x16x32_bf16(a, bfr, acc[i][nf], 0, 0, 0);
        }
      }
    }
#pragma unroll
    for(int i = 0; i < 2; i++)
#pragma unroll
      for(int nf = 0; nf < 4; nf++)
#pragma unroll
        for(int r = 0; r < 4; r++){
          int row = rt * 128 + (wid * 2 + i) * 16 + lq * 4 + r;
          int col = h * 64 + nf * 16 + lr;
          Wcpb[(size_t)row * 1024 + col] = f2bf(acc[i][nf][r]);
        }
    return;
  }
  int sel = blockIdx.y >> 3, byl = blockIdx.y & 7;
  const u16* W = sel == 0 ? Wq : sel == 1 ? Wk : Wv;
  u16* C = sel == 0 ? Q : sel == 1 ? Ko : V;
  gemm128_p2<u16>(Xb, W, C, blockIdx.x, byl, 1024, 1024);
}

__global__ __launch_bounds__(256) void out_gemm(
    const u16* __restrict__ Yb, const u16* __restrict__ Wcpb, float* __restrict__ out)
{
  gemm128_p2<float>(Yb, Wcpb, out, blockIdx.x, blockIdx.y, 1024, 1024);
}

// ---------------- state_chunk: fused K/V transpose + per-chunk state ----------------
__global__ __launch_bounds__(256) void state_chunk(
    const u16* __restrict__ Kb, const u16* __restrict__ Vb,
    u16* __restrict__ VT, float* __restrict__ Sc)
{
  int bh = blockIdx.x, c = blockIdx.y;
  int b = bh >> 4, h = bh & 15;
  int tid = threadIdx.x;
  __shared__ u16 Kt[128][72];
  __shared__ u16 Vt[128][72];
  int rr = tid >> 3;            // 0..31
  int cc = (tid & 7) * 8;       // 0..56
  const u16* kg = Kb + (size_t)(b * 2048 + c * 128) * 1024 + h * 64;
  const u16* vg = Vb + (size_t)(b * 2048 + c * 128) * 1024 + h * 64;
#pragma unroll
  for(int p = 0; p < 4; p++){
    int row = rr + p * 32;
    *(int4*)&Kt[row][cc] = *(const int4*)(kg + (size_t)row * 1024 + cc);
    *(int4*)&Vt[row][cc] = *(const int4*)(vg + (size_t)row * 1024 + cc);
  }
  __syncthreads();
  {
    int d = tid >> 2, tseg = (tid & 3) * 32;
    u16* vto = VT + (size_t)bh * 64 * 2048 + (size_t)d * 2048 + c * 128 + tseg;
#pragma unroll
    for(int j = 0; j < 32; j += 8){
      u16 tmp[8] __attribute__((aligned(16)));
#pragma unroll
      for(int q = 0; q < 8; q++) tmp[q] = Vt[tseg + j + q][d];
      *(int4*)(vto + j) = *(const int4*)tmp;
    }
  }
  int wid = tid >> 6, lane = tid & 63;
  int wr = wid >> 1, wc = wid & 1;
  int lr = lane & 15, lk8 = (lane >> 4) * 8, lq = lane >> 4;
  f32x4 acc[2][2] = {};
#pragma unroll
  for(int ks = 0; ks < 4; ks++){
    bf16x8 a[2], bb[2];
#pragma unroll
    for(int i = 0; i < 2; i++){
      u16 tmp[8] __attribute__((aligned(16)));
      int e = wr * 32 + i * 16 + lr;
#pragma unroll
      for(int q = 0; q < 8; q++) tmp[q] = Vt[ks * 32 + lk8 + q][e];
      a[i] = *(const bf16x8*)tmp;
    }
#pragma unroll
    for(int j = 0; j < 2; j++){
      u16 tmp[8] __attribute__((aligned(16)));
      int dk = wc * 32 + j * 16 + lr;
#pragma unroll
      for(int q = 0; q < 8; q++) tmp[q] = Kt[ks * 32 + lk8 + q][dk];
      bb[j] = *(const bf16x8*)tmp;
    }
#pragma unroll
    for(int i = 0; i < 2; i++)
#pragma unroll
      for(int j = 0; j < 2; j++)
        acc[i][j] = __builtin_amdgcn_mfma_f32_16x16x32_bf16(a[i], bb[j], acc[i][j], 0, 0, 0);
  }
  float* out = Sc + ((size_t)bh * 16 + c) * 4096;
#pragma unroll
  for(int i = 0; i < 2; i++)
#pragma unroll
    for(int j = 0; j < 2; j++)
#pragma unroll
      for(int r = 0; r < 4; r++){
        int e = wr * 32 + i * 16 + lq * 4 + r, dk = wc * 32 + j * 16 + lr;
        out[e * 64 + dk] = acc[i][j][r];
      }
}

// ---------------- prefix: exclusive chunk prefix, float4-vectorized ----------------
__global__ __launch_bounds__(256) void prefix_state(const float* __restrict__ Sc, u16* __restrict__ Scb)
{
  int bh = blockIdx.x >> 2, part = blockIdx.x & 3;
  int e4 = part * 256 + threadIdx.x;   // float4 index 0..1023
  const float4* s = (const float4*)(Sc + (size_t)bh * 65536) + e4;
  u16* d = Scb + (size_t)bh * 65536 + e4 * 4;
  float4 run = {0.f, 0.f, 0.f, 0.f};
  for(int c = 0; c < 16; c++){
    float4 v = s[(size_t)c * 1024];
    u64 pk = (u64)f2bf(run.x) | ((u64)f2bf(run.y) << 16) | ((u64)f2bf(run.z) << 32) | ((u64)f2bf(run.w) << 48);
    *(u64*)(d + (size_t)c * 4096) = pk;
    run.x += v.x; run.y += v.y; run.z += v.z; run.w += v.w;
  }
}

// ---------------- chunk_attn: Y = Q@stateT^T + tril(Q@K^T)@V, barrier-free ----------------
__global__ __launch_bounds__(256) void chunk_attn(
    const u16* __restrict__ Q, const u16* __restrict__ Kmat,
    const u16* __restrict__ VT, const u16* __restrict__ Scb, u16* __restrict__ Y)
{
  int bh = blockIdx.x, c = blockIdx.y;
  int b = bh >> 4, h = bh & 15;
  int t = threadIdx.x, wid = t >> 6, lane = t & 63;
  int lr = lane & 15, lk8 = (lane >> 4) * 8, lq = lane >> 4;
  __shared__ u16 S[128 * 128];  // XOR-swizzled; each wave touches only its own rows
  const u16* qg = Q    + (size_t)(b * 2048 + c * 128) * 1024 + h * 64;
  const u16* kg = Kmat + (size_t)(b * 2048 + c * 128) * 1024 + h * 64;
  const u16* scb = Scb + ((size_t)bh * 16 + c) * 4096;
  const u16* vt  = VT + (size_t)bh * 64 * 2048 + (size_t)c * 128;
  u16* yg = Y + (size_t)(b * 2048 + c * 128) * 1024 + h * 64;
#pragma unroll
  for(int mi = 0; mi < 2; mi++){
    int mf = wid + mi * 4;
    int Rm = mf * 16;
    if((mf & 1) == 0){
      int zr = Rm + (lane >> 2), zc = Rm + 16 + (lane & 3) * 4;
      int zoff = ((zr * 128 + zc) * 2) ^ ((zr & 7) << 4);
      *(u64*)((char*)S + zoff) = 0ULL;
    }
    bf16x8 a[2];
#pragma unroll
    for(int ks = 0; ks < 2; ks++) a[ks] = *(const bf16x8*)(qg + (size_t)(Rm + lr) * 1024 + ks * 32 + lk8);
    for(int nf = 0; nf <= mf; nf++){
      f32x4 acc = {};
#pragma unroll
      for(int ks = 0; ks < 2; ks++){
        bf16x8 bb = *(const bf16x8*)(kg + (size_t)(nf * 16 + lr) * 1024 + ks * 32 + lk8);
        acc = __builtin_amdgcn_mfma_f32_16x16x32_bf16(a[ks], bb, acc, 0, 0, 0);
      }
#pragma unroll
      for(int r = 0; r < 4; r++){
        int row = lq * 4 + r, col = lr;
        float v = acc[r];
        if(nf == mf && col > row) v = 0.f;
        int grow = Rm + row, gcol = nf * 16 + col;
        int off = ((grow * 128 + gcol) * 2) ^ ((grow & 7) << 4);
        *(u16*)((char*)S + off) = f2bf(v);
      }
    }
    f32x4 acc2[4] = {};
#pragma unroll
    for(int nf = 0; nf < 4; nf++){
#pragma unroll
      for(int ks = 0; ks < 2; ks++){
        bf16x8 bb = *(const bf16x8*)(scb + (nf * 16 + lr) * 64 + ks * 32 + lk8);
        acc2[nf] = __builtin_amdgcn_mfma_f32_16x16x32_bf16(a[ks], bb, acc2[nf], 0, 0, 0);
      }
    }
    int ksmax = mf >> 1;
    for(int ks = 0; ks <= ksmax; ks++){
      int row = Rm + lr;
      int off = ((row * 128 + ks * 32 + lk8) * 2) ^ ((row & 7) << 4);
      bf16x8 af = *(const bf16x8*)((char*)S + off);
#pragma unroll
      for(int nf = 0; nf < 4; nf++){
        bf16x8 bb = *(const bf16x8*)(vt + (size_t)(nf * 16 + lr) * 2048 + ks * 32 + lk8);
        acc2[nf] = __builtin_amdgcn_mfma_f32_16x16x32_bf16(af, bb, acc2[nf], 0, 0, 0);
      }
    }
#pragma unroll
    for(int nf = 0; nf < 4; nf++)
#pragma unroll
      for(int r = 0; r < 4; r++){
        int grow = Rm + lq * 4 + r, gcol = nf * 16 + lr;
        yg[(size_t)grow * 1024 + gcol] = f2bf(acc2[nf][r]);
      }
  }
}

// ---------------- launch ----------------
extern "C" void kernel_launch(void* const* d_in, const int* in_sizes, int n_in,
                              void* d_out, int out_size, void* d_ws, size_t ws_size,
                              hipStream_t stream)
{
  const float* X    = (const float*)d_in[0];
  const float* Wq   = (const float*)d_in[1];
  const float* Wk   = (const float*)d_in[2];
  const float* Wv   = (const float*)d_in[3];
  const float* Wc   = (const float*)d_in[4];
  const float* Ltri = (const float*)d_in[5];
  float* out = (float*)d_out;

  char* ws = (char*)d_ws;
  size_t off = 0;
  auto carve = [&](size_t bytes) -> char* {
    char* p = ws + off;
    off += (bytes + 255) & ~(size_t)255;
    return p;
  };
  u16* Xb   = (u16*)carve((size_t)4194304 * 2);
  u16* Wqb  = (u16*)carve((size_t)1048576 * 2);
  u16* Wkb  = (u16*)carve((size_t)1048576 * 2);
  u16* Wvb  = (u16*)carve((size_t)1048576 * 2);
  u16* Wcb  = (u16*)carve((size_t)1048576 * 2);
  u16* Wcpb = (u16*)carve((size_t)1048576 * 2);
  u16* Bmb  = (u16*)carve((size_t)65536 * 2);
  u16* Qb   = (u16*)carve((size_t)4194304 * 2);
  u16* Kb   = (u16*)carve((size_t)4194304 * 2);
  u16* Vb   = (u16*)carve((size_t)4194304 * 2);
  u16* VT   = (u16*)carve((size_t)4194304 * 2);
  float* Sc = (float*)carve((size_t)2097152 * 4);
  u16* Scb  = (u16*)carve((size_t)2097152 * 2);
  u16* Yb   = (u16*)carve((size_t)4194304 * 2);
  (void)in_sizes; (void)n_in; (void)out_size; (void)ws_size;

  prep_kernel<<<2064, 256, 0, stream>>>(X, Xb, Wq, Wqb, Wk, Wkb, Wv, Wvb, Wc, Wcb, Ltri, Bmb);
  qkv_gemm<<<dim3(32, 28), 256, 0, stream>>>(Xb, Wqb, Wkb, Wvb, Qb, Kb, Vb, Wcb, Bmb, Wcpb);
  state_chunk<<<dim3(32, 16), 256, 0, stream>>>(Kb, Vb, VT, Sc);
  prefix_state<<<128, 256, 0, stream>>>(Sc, Scb);
  chunk_attn<<<dim3(32, 16), 256, 0, stream>>>(Qb, Kb, VT, Scb, Yb);
  out_gemm<<<dim3(32, 8), 256, 0, stream>>>(Yb, Wcpb, out);
}

// Round 7
// 104.182 us; speedup vs baseline: 1.4829x; 1.0085x over previous
//
#include <hip/hip_runtime.h>

// LinearAttentionSVAR: B=2, L=2048, D=1024, H=16, d=64.
// Round 7: 256-squared 8-wave 8-phase QKV GEMM (T2+T3+T4+T5 combo).
//  - qkv8_gemm: BM=BN=256, BK=64, 512 thr (8 waves, 2M x 4N), 2 K-tile LDS
//    dbufs (128KB). Per phase: ds-read frags || stage one 16KB region ->
//    barrier -> lgkmcnt(0)+sched_barrier -> setprio(1) -> 16 MFMA ->
//    setprio(0) -> barrier. Region-staggered staging (stage a region only
//    after its last read phase); ONE vmcnt(4) per K-tile (never 0 mid-loop).
//    Row-XOR LDS swizzle (verified conflict-free in round 5): phys chunk =
//    kc ^ (row&7), linear gload_lds dest + inverse-swizzled global source.
//    N=3072 via contiguous Wq|Wk|Wv; C written to contiguous Q|K|V.
//    Wc' fold on blocks 192..255 (grid 256 = 1 block/CU).
//  - out_gemm keeps the round-6 128^2 body. prep/state/prefix/attn frozen.

#define DEV static __device__ __forceinline__

typedef unsigned short u16;
typedef unsigned long long u64;
typedef __attribute__((ext_vector_type(4))) float f32x4;
typedef __attribute__((ext_vector_type(8))) short bf16x8;

DEV u16 f2bf(float f){
  union { float f; unsigned u; } v; v.f = f;
  unsigned r = v.u + 0x7FFFu + ((v.u >> 16) & 1u);
  return (u16)(r >> 16);
}

DEV void store_val(float* p, float v){ *p = v; }
DEV void store_val(u16* p, float v){ *p = f2bf(v); }

DEV void gload16(const void* g, void* l){
  __builtin_amdgcn_global_load_lds((const __attribute__((address_space(1))) void*)g,
                                   (__attribute__((address_space(3))) void*)l, 16, 0, 0);
}

// ---------------- 1. prep: bf16 converts + per-head Bm ----------------
__global__ __launch_bounds__(256) void prep_kernel(
    const float* __restrict__ X, u16* __restrict__ Xb,
    const float* __restrict__ Wq, u16* __restrict__ Wqb,
    const float* __restrict__ Wk, u16* __restrict__ Wkb,
    const float* __restrict__ Wv, u16* __restrict__ Wvb,
    const float* __restrict__ Wc, u16* __restrict__ Wcb,
    const float* __restrict__ Ltri, u16* __restrict__ Bmb)
{
  const int bx = blockIdx.x, tid = threadIdx.x;
  if(bx < 16){
    __shared__ float Lm[64][65];
    int h = bx;
    const float* src = Ltri + (size_t)h * 4096;
    for(int i = tid; i < 4096; i += 256){
      int e = i >> 6, k = i & 63;
      Lm[e][k] = (k <= e) ? src[i] : 0.f;
    }
    __syncthreads();
    u16* out = Bmb + (size_t)h * 4096;
    for(int i = tid; i < 4096; i += 256){
      int e = i >> 6, dk = i & 63;
      float sum = 0.f;
      int kmax = e < dk ? e : dk;
      for(int k = 0; k <= kmax; k++) sum += Lm[e][k] * Lm[dk][k];
      out[i] = f2bf(sum);
    }
  } else {
    const int n0 = 4194304, n1 = 1048576, n2 = 1048576, n3 = 1048576, n4 = 1048576;
    int total = (n0 + n1 + n2 + n3 + n4) >> 2;
    for(int i = (bx - 16) * 256 + tid; i < total; i += 2048 * 256){
      int e = i << 2;
      const float* s; u16* d;
      if(e < n0){ s = X + e; d = Xb + e; }
      else if(e < n0 + n1){ s = Wq + (e - n0); d = Wqb + (e - n0); }
      else if(e < n0 + n1 + n2){ s = Wk + (e - n0 - n1); d = Wkb + (e - n0 - n1); }
      else if(e < n0 + n1 + n2 + n3){ s = Wv + (e - n0 - n1 - n2); d = Wvb + (e - n0 - n1 - n2); }
      else { s = Wc + (e - n0 - n1 - n2 - n3); d = Wcb + (e - n0 - n1 - n2 - n3); }
      float4 v = *(const float4*)s;
      u64 pk = (u64)f2bf(v.x) | ((u64)f2bf(v.y) << 16) | ((u64)f2bf(v.z) << 32) | ((u64)f2bf(v.w) << 48);
      *(u64*)d = pk;
    }
  }
}

// ---------------- 8-phase helpers ----------------
// LDS per buf: A [256 rows][8 chunks of 8 bf16] at +0, B same at +16384 elems.
// Physical chunk c of row r holds logical k-chunk kc = c ^ (r&7).
DEV bf16x8 ldsf(const u16* buf, int row, int kc){
  return *(const bf16x8*)(buf + row * 64 + ((kc ^ (row & 7)) * 8));
}
// Stage 16KB region = 128 rows x 64 cols, 2 gload16/thread.
// rsel A: 0 -> rows {0..63,128..191} (q02), 1 -> {64..127,192..255} (q13).
DEV void stageA(const u16* At, u16* bufA, int tid){
#pragma unroll
  for(int l = 0; l < 2; l++){
    int r = l * 128 + (tid >> 3);
    int c = tid & 7;
    gload16(At + (size_t)r * 1024 + (c ^ (r & 7)) * 8, bufA + r * 64 + c * 8);
  }
}
DEV void stageA1(const u16* At, u16* bufA, int tid){
#pragma unroll
  for(int l = 0; l < 2; l++){
    int r = 64 + l * 128 + (tid >> 3);
    int c = tid & 7;
    gload16(At + (size_t)r * 1024 + (c ^ (r & 7)) * 8, bufA + r * 64 + c * 8);
  }
}
// qn B regions: rows {qn*32 + 64*m + 0..31}
DEV void stageB(const u16* Wt, u16* bufB, int tid, int qn){
#pragma unroll
  for(int l = 0; l < 2; l++){
    int rr = l * 64 + (tid >> 3);
    int r = (rr >> 5) * 64 + qn * 32 + (rr & 31);
    int c = tid & 7;
    gload16(Wt + (size_t)r * 1024 + (c ^ (r & 7)) * 8, bufB + r * 64 + c * 8);
  }
}

// ---------------- qkv8: 256^2 8-phase GEMM + Wc' fold ----------------
// blocks 0..191: C[4096,3072] = Xb @ Wall^T  (Wall = Wq|Wk|Wv rows)
// blocks 192..255: Wc' fold (two 256-thread sub-blocks each).
__global__ __launch_bounds__(512, 2) void qkv8_gemm(
    const u16* __restrict__ Xb, const u16* __restrict__ Wall,
    u16* __restrict__ QKV,
    const u16* __restrict__ Wcb, const u16* __restrict__ Bmb, u16* __restrict__ Wcpb)
{
  if(blockIdx.x >= 192){
    int ob = (blockIdx.x - 192) * 2 + (threadIdx.x >> 8);
    int t = threadIdx.x & 255;
    int rt = ob & 7, h = ob >> 3;
    int lane = t & 63, wid = t >> 6;
    int lr = lane & 15, lk8 = (lane >> 4) * 8, lq = lane >> 4;
    const u16* ab  = Wcb + (size_t)(rt * 128) * 1024 + h * 64;
    const u16* bm  = Bmb + (size_t)h * 4096;
    f32x4 acc[2][4] = {};
#pragma unroll
    for(int i = 0; i < 2; i++){
      int mf = wid * 2 + i;
#pragma unroll
      for(int ks = 0; ks < 2; ks++){
        bf16x8 a = *(const bf16x8*)(ab + (size_t)(mf * 16 + lr) * 1024 + ks * 32 + lk8);
#pragma unroll
        for(int nf = 0; nf < 4; nf++){
          bf16x8 bfr = *(const bf16x8*)(bm + (nf * 16 + lr) * 64 + ks * 32 + lk8);
          acc[i][nf] = __builtin_amdgcn_mfma_f32_16x16x32_bf16(a, bfr, acc[i][nf], 0, 0, 0);
        }
      }
    }
#pragma unroll
    for(int i = 0; i < 2; i++)
#pragma unroll
      for(int nf = 0; nf < 4; nf++)
#pragma unroll
        for(int r = 0; r < 4; r++){
          int row = rt * 128 + (wid * 2 + i) * 16 + lq * 4 + r;
          int col = h * 64 + nf * 16 + lr;
          Wcpb[(size_t)row * 1024 + col] = f2bf(acc[i][nf][r]);
        }
    return;
  }

  __shared__ u16 Lds[65536];   // 128 KB: 2 dbufs x (A 16384 + B 16384) elems
  const int tid = threadIdx.x;
  const int wid = tid >> 6, lane = tid & 63;
  const int wm = wid >> 2, wn = wid & 3;
  const int lr = lane & 15, lq = lane >> 4;
  int tix = blockIdx.x;
  int tix2 = (tix & 7) * 24 + (tix >> 3);   // XCD-friendly bijection (192 = 8*24)
  int bxg = tix2 & 15, byg = tix2 >> 4;     // 16 x 12 tiles
  const u16* Ab = Xb   + (size_t)(bxg * 256) * 1024;
  const u16* Wb = Wall + (size_t)(byg * 256) * 1024;

  f32x4 acc[8][4] = {};
  bf16x8 af[4][2], b0[2][2], b1[2][2];
  const int nt = 16;

  // prologue: tile0 full (8 loads) + tile1 {A-q02, B-qn0} (4 loads)
  stageA (Ab, Lds, tid);
  stageA1(Ab, Lds, tid);
  stageB (Wb, Lds + 16384, tid, 0);
  stageB (Wb, Lds + 16384, tid, 1);
  stageA (Ab + 64, Lds + 32768, tid);
  stageB (Wb + 64, Lds + 32768 + 16384, tid, 0);
  asm volatile("s_waitcnt vmcnt(4)" ::: "memory");   // tile0 landed (12 out -> 4)
  __builtin_amdgcn_s_barrier();

  for(int t = 0; t < nt; t++){
    u16* bufA = Lds + (t & 1) * 32768;  u16* bufB = bufA + 16384;
    u16* oA   = Lds + ((t & 1) ^ 1) * 32768;  u16* oB = oA + 16384;

    // ---- phase 0: quadrant (qm=0, qn=0); stage A-q13(t+1) -> other buf ----
#pragma unroll
    for(int i = 0; i < 4; i++)
#pragma unroll
      for(int ks = 0; ks < 2; ks++)
        af[i][ks] = ldsf(bufA, wm * 128 + i * 16 + lr, ks * 4 + lq);
#pragma unroll
    for(int j = 0; j < 2; j++)
#pragma unroll
      for(int ks = 0; ks < 2; ks++)
        b0[j][ks] = ldsf(bufB, wn * 64 + j * 16 + lr, ks * 4 + lq);
    if(t + 1 < nt) stageA1(Ab + (t + 1) * 64, oA, tid);
    __builtin_amdgcn_s_barrier();
    asm volatile("s_waitcnt lgkmcnt(0)" ::: "memory");
    __builtin_amdgcn_sched_barrier(0);
    __builtin_amdgcn_s_setprio(1);
#pragma unroll
    for(int i = 0; i < 4; i++)
#pragma unroll
      for(int j = 0; j < 2; j++)
#pragma unroll
        for(int ks = 0; ks < 2; ks++)
          acc[i][j] = __builtin_amdgcn_mfma_f32_16x16x32_bf16(af[i][ks], b0[j][ks], acc[i][j], 0, 0, 0);
    __builtin_amdgcn_s_setprio(0);
    __builtin_amdgcn_s_barrier();

    // ---- phase 1: (0,1); stage B-qn1(t+1) -> other buf ----
#pragma unroll
    for(int j = 0; j < 2; j++)
#pragma unroll
      for(int ks = 0; ks < 2; ks++)
        b1[j][ks] = ldsf(bufB, wn * 64 + 32 + j * 16 + lr, ks * 4 + lq);
    if(t + 1 < nt) stageB(Wb + (t + 1) * 64, oB, tid, 1);
    __builtin_amdgcn_s_barrier();
    asm volatile("s_waitcnt lgkmcnt(0)" ::: "memory");
    __builtin_amdgcn_sched_barrier(0);
    __builtin_amdgcn_s_setprio(1);
#pragma unroll
    for(int i = 0; i < 4; i++)
#pragma unroll
      for(int j = 0; j < 2; j++)
#pragma unroll
        for(int ks = 0; ks < 2; ks++)
          acc[i][2 + j] = __builtin_amdgcn_mfma_f32_16x16x32_bf16(af[i][ks], b1[j][ks], acc[i][2 + j], 0, 0, 0);
    __builtin_amdgcn_s_setprio(0);
    __builtin_amdgcn_s_barrier();

    // ---- phase 2: (1,0); stage A-q02(t+2) -> CURRENT buf (q02 fully read) ----
#pragma unroll
    for(int i = 0; i < 4; i++)
#pragma unroll
      for(int ks = 0; ks < 2; ks++)
        af[i][ks] = ldsf(bufA, wm * 128 + 64 + i * 16 + lr, ks * 4 + lq);
    if(t + 2 < nt) stageA(Ab + (t + 2) * 64, bufA, tid);
    __builtin_amdgcn_s_barrier();
    asm volatile("s_waitcnt lgkmcnt(0)" ::: "memory");
    __builtin_amdgcn_sched_barrier(0);
    __builtin_amdgcn_s_setprio(1);
#pragma unroll
    for(int i = 0; i < 4; i++)
#pragma unroll
      for(int j = 0; j < 2; j++)
#pragma unroll
        for(int ks = 0; ks < 2; ks++)
          acc[4 + i][j] = __builtin_amdgcn_mfma_f32_16x16x32_bf16(af[i][ks], b0[j][ks], acc[4 + i][j], 0, 0, 0);
    __builtin_amdgcn_s_setprio(0);
    __builtin_amdgcn_s_barrier();

    // ---- phase 3: (1,1); stage B-qn0(t+2) -> CURRENT buf; vmcnt(4) ----
    if(t + 2 < nt) stageB(Wb + (t + 2) * 64, bufB, tid, 0);
    asm volatile("s_waitcnt vmcnt(4)" ::: "memory");  // tile t+1 fully landed
    __builtin_amdgcn_s_barrier();
    __builtin_amdgcn_s_setprio(1);
#pragma unroll
    for(int i = 0; i < 4; i++)
#pragma unroll
      for(int j = 0; j < 2; j++)
#pragma unroll
        for(int ks = 0; ks < 2; ks++)
          acc[4 + i][2 + j] = __builtin_amdgcn_mfma_f32_16x16x32_bf16(af[i][ks], b1[j][ks], acc[4 + i][2 + j], 0, 0, 0);
    __builtin_amdgcn_s_setprio(0);
    __builtin_amdgcn_s_barrier();
  }

  // C write: cols never straddle a 1024 boundary (BN=256)
  int col0 = byg * 256;
  u16* dst = QKV + (size_t)(col0 >> 10) * 4194304;
  int colin0 = col0 & 1023;
#pragma unroll
  for(int qm = 0; qm < 2; qm++)
#pragma unroll
    for(int i = 0; i < 4; i++)
#pragma unroll
      for(int qn = 0; qn < 2; qn++)
#pragma unroll
        for(int j = 0; j < 2; j++)
#pragma unroll
          for(int r = 0; r < 4; r++){
            int row = bxg * 256 + wm * 128 + qm * 64 + i * 16 + lq * 4 + r;
            int col = colin0 + wn * 64 + qn * 32 + j * 16 + lr;
            dst[(size_t)row * 1024 + col] = f2bf(acc[qm * 4 + i][qn * 2 + j][r]);
          }
}

// ---------------- out_gemm: round-6 128^2 body ----------------
template<typename OutT>
DEV void gemm128_p2(const u16* __restrict__ A, const u16* __restrict__ W,
                    OutT* __restrict__ C, int bx, int by, int N, int K)
{
  __shared__ u16 L[3][8192];
  const int tid = threadIdx.x;
  const int wid = tid >> 6, lane = tid & 63;
  const int wr = wid >> 1, wc = wid & 1;
  const int lr = lane & 15, lq = lane >> 4;
  const u16* Ag = A + (size_t)(bx * 128) * K;
  const u16* Wg = W + (size_t)(by * 128) * K;

  const int p0 = tid >> 3, p1 = 32 + (tid >> 3);
  const int cl0 = (tid & 7) ^ (p0 & 7);
  const int cl1 = (tid & 7) ^ (p1 & 7);
  const int srow0 = 2 * p0 + (cl0 >> 2), skc0 = (cl0 & 3) * 8;
  const int srow1 = 2 * p1 + (cl1 >> 2), skc1 = (cl1 & 3) * 8;

  auto stagef = [&](int kt, int buf){
    gload16(Ag + (size_t)srow0 * K + kt * 32 + skc0, &L[buf][tid * 8]);
    gload16(Ag + (size_t)srow1 * K + kt * 32 + skc1, &L[buf][2048 + tid * 8]);
    gload16(Wg + (size_t)srow0 * K + kt * 32 + skc0, &L[buf][4096 + tid * 8]);
    gload16(Wg + (size_t)srow1 * K + kt * 32 + skc1, &L[buf][6144 + tid * 8]);
  };

  const int nt = K >> 5;
  f32x4 acc[4][4] = {};
  stagef(0, 0);
  stagef(1, 1);
  int cur = 0;
  for(int t = 0; t < nt; t++){
    if(t < nt - 1) asm volatile("s_waitcnt vmcnt(4)" ::: "memory");
    else           asm volatile("s_waitcnt vmcnt(0)" ::: "memory");
    __builtin_amdgcn_s_barrier();
    __builtin_amdgcn_sched_barrier(0);
    if(t + 2 < nt){
      int n2 = cur >= 1 ? cur - 1 : cur + 2;
      stagef(t + 2, n2);
    }
    const u16* Lb = L[cur];
    bf16x8 af[4], bfr[4];
#pragma unroll
    for(int i = 0; i < 4; i++){
      int row = wr * 64 + i * 16 + lr;
      int rh = row >> 1;
      int cph = (lq | ((row & 1) << 2)) ^ (rh & 7);
      af[i] = *(const bf16x8*)&Lb[rh * 64 + cph * 8];
    }
#pragma unroll
    for(int j = 0; j < 4; j++){
      int row = wc * 64 + j * 16 + lr;
      int rh = row >> 1;
      int cph = (lq | ((row & 1) << 2)) ^ (rh & 7);
      bfr[j] = *(const bf16x8*)&Lb[4096 + rh * 64 + cph * 8];
    }
#pragma unroll
    for(int i = 0; i < 4; i++)
#pragma unroll
      for(int j = 0; j < 4; j++)
        acc[i][j] = __builtin_amdgcn_mfma_f32_16x16x32_bf16(af[i], bfr[j], acc[i][j], 0, 0, 0);
    cur = cur == 2 ? 0 : cur + 1;
  }
#pragma unroll
  for(int i = 0; i < 4; i++)
#pragma unroll
    for(int j = 0; j < 4; j++)
#pragma unroll
      for(int r = 0; r < 4; r++){
        int row = bx * 128 + wr * 64 + i * 16 + (lane >> 4) * 4 + r;
        int col = by * 128 + wc * 64 + j * 16 + lr;
        store_val(C + (size_t)row * N + col, acc[i][j][r]);
      }
}

__global__ __launch_bounds__(256) void out_gemm(
    const u16* __restrict__ Yb, const u16* __restrict__ Wcpb, float* __restrict__ out)
{
  gemm128_p2<float>(Yb, Wcpb, out, blockIdx.x, blockIdx.y, 1024, 1024);
}

// ---------------- state_chunk ----------------
__global__ __launch_bounds__(256) void state_chunk(
    const u16* __restrict__ Kb, const u16* __restrict__ Vb,
    u16* __restrict__ VT, float* __restrict__ Sc)
{
  int bh = blockIdx.x, c = blockIdx.y;
  int b = bh >> 4, h = bh & 15;
  int tid = threadIdx.x;
  __shared__ u16 Kt[128][72];
  __shared__ u16 Vt[128][72];
  int rr = tid >> 3;
  int cc = (tid & 7) * 8;
  const u16* kg = Kb + (size_t)(b * 2048 + c * 128) * 1024 + h * 64;
  const u16* vg = Vb + (size_t)(b * 2048 + c * 128) * 1024 + h * 64;
#pragma unroll
  for(int p = 0; p < 4; p++){
    int row = rr + p * 32;
    *(int4*)&Kt[row][cc] = *(const int4*)(kg + (size_t)row * 1024 + cc);
    *(int4*)&Vt[row][cc] = *(const int4*)(vg + (size_t)row * 1024 + cc);
  }
  __syncthreads();
  {
    int d = tid >> 2, tseg = (tid & 3) * 32;
    u16* vto = VT + (size_t)bh * 64 * 2048 + (size_t)d * 2048 + c * 128 + tseg;
#pragma unroll
    for(int j = 0; j < 32; j += 8){
      u16 tmp[8] __attribute__((aligned(16)));
#pragma unroll
      for(int q = 0; q < 8; q++) tmp[q] = Vt[tseg + j + q][d];
      *(int4*)(vto + j) = *(const int4*)tmp;
    }
  }
  int wid = tid >> 6, lane = tid & 63;
  int wr = wid >> 1, wc = wid & 1;
  int lr = lane & 15, lk8 = (lane >> 4) * 8, lq = lane >> 4;
  f32x4 acc[2][2] = {};
#pragma unroll
  for(int ks = 0; ks < 4; ks++){
    bf16x8 a[2], bb[2];
#pragma unroll
    for(int i = 0; i < 2; i++){
      u16 tmp[8] __attribute__((aligned(16)));
      int e = wr * 32 + i * 16 + lr;
#pragma unroll
      for(int q = 0; q < 8; q++) tmp[q] = Vt[ks * 32 + lk8 + q][e];
      a[i] = *(const bf16x8*)tmp;
    }
#pragma unroll
    for(int j = 0; j < 2; j++){
      u16 tmp[8] __attribute__((aligned(16)));
      int dk = wc * 32 + j * 16 + lr;
#pragma unroll
      for(int q = 0; q < 8; q++) tmp[q] = Kt[ks * 32 + lk8 + q][dk];
      bb[j] = *(const bf16x8*)tmp;
    }
#pragma unroll
    for(int i = 0; i < 2; i++)
#pragma unroll
      for(int j = 0; j < 2; j++)
        acc[i][j] = __builtin_amdgcn_mfma_f32_16x16x32_bf16(a[i], bb[j], acc[i][j], 0, 0, 0);
  }
  float* out = Sc + ((size_t)bh * 16 + c) * 4096;
#pragma unroll
  for(int i = 0; i < 2; i++)
#pragma unroll
    for(int j = 0; j < 2; j++)
#pragma unroll
      for(int r = 0; r < 4; r++){
        int e = wr * 32 + i * 16 + lq * 4 + r, dk = wc * 32 + j * 16 + lr;
        out[e * 64 + dk] = acc[i][j][r];
      }
}

// ---------------- prefix ----------------
__global__ __launch_bounds__(256) void prefix_state(const float* __restrict__ Sc, u16* __restrict__ Scb)
{
  int bh = blockIdx.x >> 2, part = blockIdx.x & 3;
  int e4 = part * 256 + threadIdx.x;
  const float4* s = (const float4*)(Sc + (size_t)bh * 65536) + e4;
  u16* d = Scb + (size_t)bh * 65536 + e4 * 4;
  float4 run = {0.f, 0.f, 0.f, 0.f};
  for(int c = 0; c < 16; c++){
    float4 v = s[(size_t)c * 1024];
    u64 pk = (u64)f2bf(run.x) | ((u64)f2bf(run.y) << 16) | ((u64)f2bf(run.z) << 32) | ((u64)f2bf(run.w) << 48);
    *(u64*)(d + (size_t)c * 4096) = pk;
    run.x += v.x; run.y += v.y; run.z += v.z; run.w += v.w;
  }
}

// ---------------- chunk_attn ----------------
__global__ __launch_bounds__(256) void chunk_attn(
    const u16* __restrict__ Q, const u16* __restrict__ Kmat,
    const u16* __restrict__ VT, const u16* __restrict__ Scb, u16* __restrict__ Y)
{
  int bh = blockIdx.x, c = blockIdx.y;
  int b = bh >> 4, h = bh & 15;
  int t = threadIdx.x, wid = t >> 6, lane = t & 63;
  int lr = lane & 15, lk8 = (lane >> 4) * 8, lq = lane >> 4;
  __shared__ u16 S[128 * 128];
  const u16* qg = Q    + (size_t)(b * 2048 + c * 128) * 1024 + h * 64;
  const u16* kg = Kmat + (size_t)(b * 2048 + c * 128) * 1024 + h * 64;
  const u16* scb = Scb + ((size_t)bh * 16 + c) * 4096;
  const u16* vt  = VT + (size_t)bh * 64 * 2048 + (size_t)c * 128;
  u16* yg = Y + (size_t)(b * 2048 + c * 128) * 1024 + h * 64;
#pragma unroll
  for(int mi = 0; mi < 2; mi++){
    int mf = wid + mi * 4;
    int Rm = mf * 16;
    if((mf & 1) == 0){
      int zr = Rm + (lane >> 2), zc = Rm + 16 + (lane & 3) * 4;
      int zoff = ((zr * 128 + zc) * 2) ^ ((zr & 7) << 4);
      *(u64*)((char*)S + zoff) = 0ULL;
    }
    bf16x8 a[2];
#pragma unroll
    for(int ks = 0; ks < 2; ks++) a[ks] = *(const bf16x8*)(qg + (size_t)(Rm + lr) * 1024 + ks * 32 + lk8);
    for(int nf = 0; nf <= mf; nf++){
      f32x4 acc = {};
#pragma unroll
      for(int ks = 0; ks < 2; ks++){
        bf16x8 bb = *(const bf16x8*)(kg + (size_t)(nf * 16 + lr) * 1024 + ks * 32 + lk8);
        acc = __builtin_amdgcn_mfma_f32_16x16x32_bf16(a[ks], bb, acc, 0, 0, 0);
      }
#pragma unroll
      for(int r = 0; r < 4; r++){
        int row = lq * 4 + r, col = lr;
        float v = acc[r];
        if(nf == mf && col > row) v = 0.f;
        int grow = Rm + row, gcol = nf * 16 + col;
        int off = ((grow * 128 + gcol) * 2) ^ ((grow & 7) << 4);
        *(u16*)((char*)S + off) = f2bf(v);
      }
    }
    f32x4 acc2[4] = {};
#pragma unroll
    for(int nf = 0; nf < 4; nf++){
#pragma unroll
      for(int ks = 0; ks < 2; ks++){
        bf16x8 bb = *(const bf16x8*)(scb + (nf * 16 + lr) * 64 + ks * 32 + lk8);
        acc2[nf] = __builtin_amdgcn_mfma_f32_16x16x32_bf16(a[ks], bb, acc2[nf], 0, 0, 0);
      }
    }
    int ksmax = mf >> 1;
    for(int ks = 0; ks <= ksmax; ks++){
      int row = Rm + lr;
      int off = ((row * 128 + ks * 32 + lk8) * 2) ^ ((row & 7) << 4);
      bf16x8 af = *(const bf16x8*)((char*)S + off);
#pragma unroll
      for(int nf = 0; nf < 4; nf++){
        bf16x8 bb = *(const bf16x8*)(vt + (size_t)(nf * 16 + lr) * 2048 + ks * 32 + lk8);
        acc2[nf] = __builtin_amdgcn_mfma_f32_16x16x32_bf16(af, bb, acc2[nf], 0, 0, 0);
      }
    }
#pragma unroll
    for(int nf = 0; nf < 4; nf++)
#pragma unroll
      for(int r = 0; r < 4; r++){
        int grow = Rm + lq * 4 + r, gcol = nf * 16 + lr;
        yg[(size_t)grow * 1024 + gcol] = f2bf(acc2[nf][r]);
      }
  }
}

// ---------------- launch ----------------
extern "C" void kernel_launch(void* const* d_in, const int* in_sizes, int n_in,
                              void* d_out, int out_size, void* d_ws, size_t ws_size,
                              hipStream_t stream)
{
  const float* X    = (const float*)d_in[0];
  const float* Wq   = (const float*)d_in[1];
  const float* Wk   = (const float*)d_in[2];
  const float* Wv   = (const float*)d_in[3];
  const float* Wc   = (const float*)d_in[4];
  const float* Ltri = (const float*)d_in[5];
  float* out = (float*)d_out;

  char* ws = (char*)d_ws;
  size_t off = 0;
  auto carve = [&](size_t bytes) -> char* {
    char* p = ws + off;
    off += (bytes + 255) & ~(size_t)255;
    return p;
  };
  u16* Xb   = (u16*)carve((size_t)4194304 * 2);
  u16* Wqb  = (u16*)carve((size_t)1048576 * 2);  // Wqb|Wkb|Wvb contiguous = Wall
  u16* Wkb  = (u16*)carve((size_t)1048576 * 2);
  u16* Wvb  = (u16*)carve((size_t)1048576 * 2);
  u16* Wcb  = (u16*)carve((size_t)1048576 * 2);
  u16* Wcpb = (u16*)carve((size_t)1048576 * 2);
  u16* Bmb  = (u16*)carve((size_t)65536 * 2);
  u16* Qb   = (u16*)carve((size_t)4194304 * 2);  // Qb|Kb|Vb contiguous = QKV
  u16* Kb   = (u16*)carve((size_t)4194304 * 2);
  u16* Vb   = (u16*)carve((size_t)4194304 * 2);
  u16* VT   = (u16*)carve((size_t)4194304 * 2);
  float* Sc = (float*)carve((size_t)2097152 * 4);
  u16* Scb  = (u16*)carve((size_t)2097152 * 2);
  u16* Yb   = (u16*)carve((size_t)4194304 * 2);
  (void)in_sizes; (void)n_in; (void)out_size; (void)ws_size;

  prep_kernel<<<2064, 256, 0, stream>>>(X, Xb, Wq, Wqb, Wk, Wkb, Wv, Wvb, Wc, Wcb, Ltri, Bmb);
  qkv8_gemm<<<256, 512, 0, stream>>>(Xb, Wqb, Qb, Wcb, Bmb, Wcpb);
  state_chunk<<<dim3(32, 16), 256, 0, stream>>>(Kb, Vb, VT, Sc);
  prefix_state<<<128, 256, 0, stream>>>(Sc, Scb);
  chunk_attn<<<dim3(32, 16), 256, 0, stream>>>(Qb, Kb, VT, Scb, Yb);
  out_gemm<<<dim3(32, 8), 256, 0, stream>>>(Yb, Wcpb, out);
}